// Round 1
// baseline (784.524 us; speedup 1.0000x reference)
//
#include <hip/hip_runtime.h>
#include <math.h>

#define N_NODES 50000
#define N_EDGES 800000
#define ETOT    850000   // N_EDGES + N_NODES self-loops
#define GRAPHS  64
#define FIN     128
#define HC      128      // HEADS*HID
#define OUTF    10
#define NEG     0.2f

// ---------------- init ----------------
__global__ void initk(int* deg, int* fill, float* sums, int* cnt) {
    int i = blockIdx.x * 256 + threadIdx.x;
    if (i < N_NODES) { deg[i] = 1; fill[i] = 0; }   // deg starts at 1: self-loop
    if (i < GRAPHS * HC) sums[i] = 0.f;
    if (i < GRAPHS) cnt[i] = 0;
}

// ---------------- degree count (real edges only) ----------------
__global__ void degk(const int* __restrict__ ei, int* deg) {
    int e = blockIdx.x * 256 + threadIdx.x;
    if (e < N_EDGES) atomicAdd(&deg[ei[N_EDGES + e]], 1);
}

// ---------------- 3-kernel exclusive scan over deg -> rowptr ----------------
__global__ void scan1(const int* __restrict__ deg, int* tmp, int* bsum) {
    __shared__ int sh[256];
    int t = threadIdx.x;
    int i = blockIdx.x * 256 + t;
    int v = (i < N_NODES) ? deg[i] : 0;
    sh[t] = v;
    __syncthreads();
    for (int off = 1; off < 256; off <<= 1) {
        int add = (t >= off) ? sh[t - off] : 0;
        __syncthreads();
        sh[t] += add;
        __syncthreads();
    }
    if (i < N_NODES) tmp[i] = sh[t];
    if (t == 255) bsum[blockIdx.x] = sh[255];
}

__global__ void scan2(int* bsum, int nb) {
    __shared__ int sh[256];
    int t = threadIdx.x;
    int v = (t < nb) ? bsum[t] : 0;
    sh[t] = v;
    __syncthreads();
    for (int off = 1; off < 256; off <<= 1) {
        int add = (t >= off) ? sh[t - off] : 0;
        __syncthreads();
        sh[t] += add;
        __syncthreads();
    }
    if (t < nb) bsum[t] = sh[t] - v;   // exclusive
}

__global__ void scan3(const int* __restrict__ tmp, const int* __restrict__ bsum, int* rowptr) {
    int i = blockIdx.x * 256 + threadIdx.x;
    if (i < N_NODES) rowptr[i + 1] = tmp[i] + bsum[blockIdx.x];
    if (i == 0) rowptr[0] = 0;
}

// ---------------- CSR fill (incl. self-loops) ----------------
__global__ void fillk(const int* __restrict__ ei, const int* __restrict__ rowptr,
                      int* fill, int* csr) {
    int e = blockIdx.x * 256 + threadIdx.x;
    if (e >= ETOT) return;
    int s, d;
    if (e < N_EDGES) { s = ei[e]; d = ei[N_EDGES + e]; }
    else             { s = d = e - N_EDGES; }
    int pos = rowptr[d] + atomicAdd(&fill[d], 1);
    csr[pos] = s;
}

// ---------------- GEMM: Y[M,128] = X[M,128] @ W[128,128] ----------------
__global__ __launch_bounds__(256) void gemm128(const float* __restrict__ X,
                                               const float* __restrict__ W,
                                               float* __restrict__ Y) {
    __shared__ float xs[8][128];
    int t = threadIdx.x;
    int r0 = blockIdx.x * 8;
    {
        int idx = t * 4;
        int rr = idx >> 7, cc = idx & 127;
        *(float4*)&xs[rr][cc] = *(const float4*)&X[(size_t)(r0 + rr) * 128 + cc];
    }
    __syncthreads();
    int r = t >> 5;
    int c4 = (t & 31) * 4;
    float4 acc = {0.f, 0.f, 0.f, 0.f};
#pragma unroll 8
    for (int k = 0; k < 128; ++k) {
        float xv = xs[r][k];
        float4 wv = *(const float4*)&W[k * 128 + c4];
        acc.x += xv * wv.x; acc.y += xv * wv.y;
        acc.z += xv * wv.z; acc.w += xv * wv.w;
    }
    *(float4*)&Y[(size_t)(r0 + r) * 128 + c4] = acc;
}

// ---------------- attention scores: one wave per node ----------------
__global__ __launch_bounds__(256) void attscore(const float* __restrict__ H,
                                                const float* __restrict__ att_s,
                                                const float* __restrict__ att_d,
                                                float2* __restrict__ a_src,
                                                float2* __restrict__ a_dst) {
    int wid = (blockIdx.x * 256 + threadIdx.x) >> 6;
    int lane = threadIdx.x & 63;
    if (wid >= N_NODES) return;
    float2 hv  = *(const float2*)&H[(size_t)wid * 128 + lane * 2];
    float2 asv = *(const float2*)&att_s[lane * 2];
    float2 adv = *(const float2*)&att_d[lane * 2];
    float ps = hv.x * asv.x + hv.y * asv.y;
    float pd = hv.x * adv.x + hv.y * adv.y;
    // lanes 0-31 hold head0 partials (f 0..63), lanes 32-63 head1
    for (int off = 1; off < 32; off <<= 1) {
        ps += __shfl_xor(ps, off);
        pd += __shfl_xor(pd, off);
    }
    float ps1 = __shfl(ps, 32);
    float pd1 = __shfl(pd, 32);
    if (lane == 0) {
        a_src[wid] = make_float2(ps, ps1);
        a_dst[wid] = make_float2(pd, pd1);
    }
}

__device__ __forceinline__ float leaky(float x) { return x > 0.f ? x : NEG * x; }

// ---------------- softmax + aggregation: one wave per dst node ----------------
__global__ __launch_bounds__(256) void aggk(const float* __restrict__ H,
                                            const float2* __restrict__ a_src,
                                            const float2* __restrict__ a_dst,
                                            const int* __restrict__ rowptr,
                                            const int* __restrict__ csr,
                                            const float* __restrict__ bias,
                                            float* __restrict__ outp) {
    int wid = (blockIdx.x * 256 + threadIdx.x) >> 6;
    int lane = threadIdx.x & 63;
    if (wid >= N_NODES) return;
    int rbeg = rowptr[wid], rend = rowptr[wid + 1];
    float2 ad = a_dst[wid];

    // pass 1: per-head max (lane-parallel over edges)
    float m0 = -1e30f, m1 = -1e30f;
    for (int j = rbeg + lane; j < rend; j += 64) {
        int s = csr[j];
        float2 as = a_src[s];
        m0 = fmaxf(m0, leaky(as.x + ad.x));
        m1 = fmaxf(m1, leaky(as.y + ad.y));
    }
    for (int off = 32; off; off >>= 1) {
        m0 = fmaxf(m0, __shfl_xor(m0, off));
        m1 = fmaxf(m1, __shfl_xor(m1, off));
    }
    // pass 2: denom
    float d0 = 0.f, d1 = 0.f;
    for (int j = rbeg + lane; j < rend; j += 64) {
        int s = csr[j];
        float2 as = a_src[s];
        d0 += __expf(leaky(as.x + ad.x) - m0);
        d1 += __expf(leaky(as.y + ad.y) - m1);
    }
    for (int off = 32; off; off >>= 1) {
        d0 += __shfl_xor(d0, off);
        d1 += __shfl_xor(d1, off);
    }
    float inv0 = 1.f / (d0 + 1e-16f), inv1 = 1.f / (d1 + 1e-16f);

    // pass 3: weighted accumulation; lane covers features 2*lane, 2*lane+1
    int head = lane >> 5;
    float mh   = head ? m1 : m0;
    float invh = head ? inv1 : inv0;
    float adh  = head ? ad.y : ad.x;
    int f = lane * 2;
    float2 acc = {0.f, 0.f};
    for (int j = rbeg; j < rend; ++j) {
        int s = csr[j];
        float2 as = a_src[s];
        float e = leaky((head ? as.y : as.x) + adh);
        float w = __expf(e - mh) * invh;
        float2 hv = *(const float2*)&H[(size_t)s * 128 + f];
        acc.x += w * hv.x;
        acc.y += w * hv.y;
    }
    float2 bb = *(const float2*)&bias[f];
    float2 o;
    o.x = fmaxf(acc.x + bb.x, 0.f);
    o.y = fmaxf(acc.y + bb.y, 0.f);
    *(float2*)&outp[(size_t)wid * 128 + f] = o;
}

// ---------------- pooling ----------------
__global__ void countk(const int* __restrict__ batch, int* cnt) {
    int i = blockIdx.x * 256 + threadIdx.x;
    if (i < N_NODES) atomicAdd(&cnt[batch[i]], 1);
}

__global__ void poolk(const float* __restrict__ H, const int* __restrict__ batch,
                      float* __restrict__ sums) {
    int f = threadIdx.x;            // 128 threads
    int n0 = blockIdx.x * 64;
    if (n0 >= N_NODES) return;
    int n1 = min(n0 + 64, N_NODES);
    int g = batch[n0];
    float run = 0.f;
    for (int n = n0; n < n1; ++n) {
        int gn = batch[n];
        if (gn != g) { atomicAdd(&sums[g * 128 + f], run); run = 0.f; g = gn; }
        run += H[(size_t)n * 128 + f];
    }
    atomicAdd(&sums[g * 128 + f], run);
}

__global__ void finalk(const float* __restrict__ sums, const int* __restrict__ cnt,
                       const float* __restrict__ Wl, const float* __restrict__ bl,
                       float* __restrict__ out) {
    int t = threadIdx.x;
    if (t >= GRAPHS * OUTF) return;
    int g = t / OUTF, o = t % OUTF;
    float inv = 1.f / fmaxf((float)cnt[g], 1.f);
    float acc = 0.f;
#pragma unroll 8
    for (int k = 0; k < 128; ++k) acc += sums[g * 128 + k] * Wl[k * OUTF + o];
    out[t] = acc * inv + bl[o];
}

extern "C" void kernel_launch(void* const* d_in, const int* in_sizes, int n_in,
                              void* d_out, int out_size, void* d_ws, size_t ws_size,
                              hipStream_t stream) {
    const float* x        = (const float*)d_in[0];
    const int*   ei       = (const int*)d_in[1];
    const int*   batch    = (const int*)d_in[2];
    const float* W1       = (const float*)d_in[3];
    const float* att_src1 = (const float*)d_in[4];
    const float* att_dst1 = (const float*)d_in[5];
    const float* b1       = (const float*)d_in[6];
    const float* W2       = (const float*)d_in[7];
    const float* att_src2 = (const float*)d_in[8];
    const float* att_dst2 = (const float*)d_in[9];
    const float* b2       = (const float*)d_in[10];
    const float* Wl       = (const float*)d_in[11];
    const float* bl       = (const float*)d_in[12];
    float* out = (float*)d_out;

    size_t off = 0;
    auto alloc = [&](size_t bytes) -> void* {
        void* p = (char*)d_ws + off;
        off = (off + bytes + 255) & ~(size_t)255;
        return p;
    };
    float*  A      = (float*)alloc((size_t)N_NODES * 128 * 4);
    float*  B      = (float*)alloc((size_t)N_NODES * 128 * 4);
    float2* a_src  = (float2*)alloc((size_t)N_NODES * 8);
    float2* a_dst  = (float2*)alloc((size_t)N_NODES * 8);
    int*    deg    = (int*)alloc((size_t)N_NODES * 4);
    int*    fill   = (int*)alloc((size_t)N_NODES * 4);
    int*    tmp    = (int*)alloc((size_t)N_NODES * 4);
    int*    bsum   = (int*)alloc(256 * 4);
    int*    rowptr = (int*)alloc((size_t)(N_NODES + 1) * 4);
    int*    csr    = (int*)alloc((size_t)ETOT * 4);
    float*  sums   = (float*)alloc((size_t)GRAPHS * HC * 4);
    int*    cnt    = (int*)alloc(GRAPHS * 4);

    const int nbN = (N_NODES + 255) / 256;      // 196

    // ---- CSR build (shared by both layers) ----
    initk<<<nbN, 256, 0, stream>>>(deg, fill, sums, cnt);
    degk<<<(N_EDGES + 255) / 256, 256, 0, stream>>>(ei, deg);
    scan1<<<nbN, 256, 0, stream>>>(deg, tmp, bsum);
    scan2<<<1, 256, 0, stream>>>(bsum, nbN);
    scan3<<<nbN, 256, 0, stream>>>(tmp, bsum, rowptr);
    fillk<<<(ETOT + 255) / 256, 256, 0, stream>>>(ei, rowptr, fill, csr);

    const int gemmBlocks = N_NODES / 8;          // 6250, exact
    const int waveBlocks = (N_NODES * 64 + 255) / 256;   // 12500

    // ---- layer 1 ----
    gemm128<<<gemmBlocks, 256, 0, stream>>>(x, W1, A);
    attscore<<<waveBlocks, 256, 0, stream>>>(A, att_src1, att_dst1, a_src, a_dst);
    aggk<<<waveBlocks, 256, 0, stream>>>(A, a_src, a_dst, rowptr, csr, b1, B);

    // ---- layer 2 ----
    gemm128<<<gemmBlocks, 256, 0, stream>>>(B, W2, A);
    attscore<<<waveBlocks, 256, 0, stream>>>(A, att_src2, att_dst2, a_src, a_dst);
    aggk<<<waveBlocks, 256, 0, stream>>>(A, a_src, a_dst, rowptr, csr, b2, B);

    // ---- pool + final linear ----
    countk<<<nbN, 256, 0, stream>>>(batch, cnt);
    poolk<<<(N_NODES + 63) / 64, 128, 0, stream>>>(B, batch, sums);
    finalk<<<1, 640, 0, stream>>>(sums, cnt, Wl, bl, out);
}

// Round 2
// 542.726 us; speedup vs baseline: 1.4455x; 1.4455x over previous
//
#include <hip/hip_runtime.h>
#include <math.h>

#define N_NODES 50000
#define N_EDGES 800000
#define ETOT    850000   // N_EDGES + N_NODES self-loops
#define GRAPHS  64
#define FIN     128
#define HC      128      // HEADS*HID
#define OUTF    10
#define NEG     0.2f

// ---------------- init ----------------
__global__ void initk(int* deg, int* fill, float* sums) {
    int i = blockIdx.x * 256 + threadIdx.x;
    if (i < N_NODES) { deg[i] = 1; fill[i] = 0; }   // deg starts at 1: self-loop
    if (i < GRAPHS * HC) sums[i] = 0.f;
}

// ---------------- degree count (real edges only) ----------------
__global__ void degk(const int* __restrict__ ei, int* deg) {
    int e = blockIdx.x * 256 + threadIdx.x;
    if (e < N_EDGES) atomicAdd(&deg[ei[N_EDGES + e]], 1);
}

// ---------------- 3-kernel exclusive scan over deg -> rowptr ----------------
__global__ void scan1(const int* __restrict__ deg, int* tmp, int* bsum) {
    __shared__ int sh[256];
    int t = threadIdx.x;
    int i = blockIdx.x * 256 + t;
    int v = (i < N_NODES) ? deg[i] : 0;
    sh[t] = v;
    __syncthreads();
    for (int off = 1; off < 256; off <<= 1) {
        int add = (t >= off) ? sh[t - off] : 0;
        __syncthreads();
        sh[t] += add;
        __syncthreads();
    }
    if (i < N_NODES) tmp[i] = sh[t];
    if (t == 255) bsum[blockIdx.x] = sh[255];
}

__global__ void scan2(int* bsum, int nb) {
    __shared__ int sh[256];
    int t = threadIdx.x;
    int v = (t < nb) ? bsum[t] : 0;
    sh[t] = v;
    __syncthreads();
    for (int off = 1; off < 256; off <<= 1) {
        int add = (t >= off) ? sh[t - off] : 0;
        __syncthreads();
        sh[t] += add;
        __syncthreads();
    }
    if (t < nb) bsum[t] = sh[t] - v;   // exclusive
}

__global__ void scan3(const int* __restrict__ tmp, const int* __restrict__ bsum, int* rowptr) {
    int i = blockIdx.x * 256 + threadIdx.x;
    if (i < N_NODES) rowptr[i + 1] = tmp[i] + bsum[blockIdx.x];
    if (i == 0) rowptr[0] = 0;
}

// ---------------- CSR fill (incl. self-loops) ----------------
__global__ void fillk(const int* __restrict__ ei, const int* __restrict__ rowptr,
                      int* fill, int* csr) {
    int e = blockIdx.x * 256 + threadIdx.x;
    if (e >= ETOT) return;
    int s, d;
    if (e < N_EDGES) { s = ei[e]; d = ei[N_EDGES + e]; }
    else             { s = d = e - N_EDGES; }
    int pos = rowptr[d] + atomicAdd(&fill[d], 1);
    csr[pos] = s;
}

// ---------------- GEMM + fused attention scores ----------------
// Y[M,128] = X[M,128] @ W[128,128]; a_src/a_dst per row from epilogue regs
__global__ __launch_bounds__(256) void gemm128att(const float* __restrict__ X,
                                                  const float* __restrict__ W,
                                                  const float* __restrict__ att_s,
                                                  const float* __restrict__ att_d,
                                                  float* __restrict__ Y,
                                                  float2* __restrict__ a_src,
                                                  float2* __restrict__ a_dst) {
    __shared__ float xs[8][128];
    int t = threadIdx.x;
    int r0 = blockIdx.x * 8;
    {
        int idx = t * 4;
        int rr = idx >> 7, cc = idx & 127;
        *(float4*)&xs[rr][cc] = *(const float4*)&X[(size_t)(r0 + rr) * 128 + cc];
    }
    __syncthreads();
    int r = t >> 5;
    int c4 = (t & 31) * 4;
    float4 acc = {0.f, 0.f, 0.f, 0.f};
#pragma unroll 8
    for (int k = 0; k < 128; ++k) {
        float xv = xs[r][k];
        float4 wv = *(const float4*)&W[k * 128 + c4];
        acc.x += xv * wv.x; acc.y += xv * wv.y;
        acc.z += xv * wv.z; acc.w += xv * wv.w;
    }
    *(float4*)&Y[(size_t)(r0 + r) * 128 + c4] = acc;

    // fused attention scores: row-group = 32 lanes; head0 = group-lanes 0-15,
    // head1 = group-lanes 16-31 (c4 >= 64)
    float4 sv = *(const float4*)&att_s[c4];
    float4 dv = *(const float4*)&att_d[c4];
    float ps = acc.x * sv.x + acc.y * sv.y + acc.z * sv.z + acc.w * sv.w;
    float pd = acc.x * dv.x + acc.y * dv.y + acc.z * dv.z + acc.w * dv.w;
    for (int off = 1; off < 16; off <<= 1) {
        ps += __shfl_xor(ps, off);
        pd += __shfl_xor(pd, off);
    }
    int lane = t & 63;
    float ps1 = __shfl(ps, (lane & 32) + 16);   // head1 sum lives at group-lane 16
    float pd1 = __shfl(pd, (lane & 32) + 16);
    if ((lane & 31) == 0) {
        a_src[r0 + r] = make_float2(ps, ps1);
        a_dst[r0 + r] = make_float2(pd, pd1);
    }
}

__device__ __forceinline__ float leaky(float x) { return x > 0.f ? x : NEG * x; }

// ---------------- softmax + aggregation: one wave per dst node ----------------
__global__ __launch_bounds__(256) void aggk(const float* __restrict__ H,
                                            const float2* __restrict__ a_src,
                                            const float2* __restrict__ a_dst,
                                            const int* __restrict__ rowptr,
                                            const int* __restrict__ csr,
                                            const float* __restrict__ bias,
                                            float* __restrict__ outp) {
    int wid = (blockIdx.x * 256 + threadIdx.x) >> 6;
    int lane = threadIdx.x & 63;
    if (wid >= N_NODES) return;
    int rbeg = rowptr[wid], rend = rowptr[wid + 1];
    float2 ad = a_dst[wid];

    // pass 1: per-head max (lane-parallel over edges)
    float m0 = -1e30f, m1 = -1e30f;
    for (int j = rbeg + lane; j < rend; j += 64) {
        int s = csr[j];
        float2 as = a_src[s];
        m0 = fmaxf(m0, leaky(as.x + ad.x));
        m1 = fmaxf(m1, leaky(as.y + ad.y));
    }
    for (int off = 32; off; off >>= 1) {
        m0 = fmaxf(m0, __shfl_xor(m0, off));
        m1 = fmaxf(m1, __shfl_xor(m1, off));
    }
    // pass 2: denom
    float d0 = 0.f, d1 = 0.f;
    for (int j = rbeg + lane; j < rend; j += 64) {
        int s = csr[j];
        float2 as = a_src[s];
        d0 += __expf(leaky(as.x + ad.x) - m0);
        d1 += __expf(leaky(as.y + ad.y) - m1);
    }
    for (int off = 32; off; off >>= 1) {
        d0 += __shfl_xor(d0, off);
        d1 += __shfl_xor(d1, off);
    }
    float inv0 = 1.f / (d0 + 1e-16f), inv1 = 1.f / (d1 + 1e-16f);

    // pass 3: weighted accumulation; lane covers features 2*lane, 2*lane+1
    int head = lane >> 5;
    float mh   = head ? m1 : m0;
    float invh = head ? inv1 : inv0;
    float adh  = head ? ad.y : ad.x;
    int f = lane * 2;
    float2 acc = {0.f, 0.f};
    for (int j = rbeg; j < rend; ++j) {
        int s = csr[j];
        float2 as = a_src[s];
        float e = leaky((head ? as.y : as.x) + adh);
        float w = __expf(e - mh) * invh;
        float2 hv = *(const float2*)&H[(size_t)s * 128 + f];
        acc.x += w * hv.x;
        acc.y += w * hv.y;
    }
    float2 bb = *(const float2*)&bias[f];
    float2 o;
    o.x = fmaxf(acc.x + bb.x, 0.f);
    o.y = fmaxf(acc.y + bb.y, 0.f);
    *(float2*)&outp[(size_t)wid * 128 + f] = o;
}

// ---------------- pooling ----------------
// batch is sorted: count via binary search, no atomics.
__global__ void countk(const int* __restrict__ batch, int* cnt) {
    int g = threadIdx.x;
    if (g >= GRAPHS) return;
    int lo = 0, hi = N_NODES;
    while (lo < hi) { int mid = (lo + hi) >> 1; if (batch[mid] < g) lo = mid + 1; else hi = mid; }
    int lb = lo;
    lo = 0; hi = N_NODES;
    while (lo < hi) { int mid = (lo + hi) >> 1; if (batch[mid] < g + 1) lo = mid + 1; else hi = mid; }
    cnt[g] = lo - lb;
}

__global__ void poolk(const float* __restrict__ H, const int* __restrict__ batch,
                      float* __restrict__ sums) {
    int f = threadIdx.x;            // 128 threads
    int n0 = blockIdx.x * 64;
    if (n0 >= N_NODES) return;
    int n1 = min(n0 + 64, N_NODES);
    int g = batch[n0];
    float run = 0.f;
    for (int n = n0; n < n1; ++n) {
        int gn = batch[n];
        if (gn != g) { atomicAdd(&sums[g * 128 + f], run); run = 0.f; g = gn; }
        run += H[(size_t)n * 128 + f];
    }
    atomicAdd(&sums[g * 128 + f], run);
}

__global__ void finalk(const float* __restrict__ sums, const int* __restrict__ cnt,
                       const float* __restrict__ Wl, const float* __restrict__ bl,
                       float* __restrict__ out) {
    int t = threadIdx.x;
    if (t >= GRAPHS * OUTF) return;
    int g = t / OUTF, o = t % OUTF;
    float inv = 1.f / fmaxf((float)cnt[g], 1.f);
    float acc = 0.f;
#pragma unroll 8
    for (int k = 0; k < 128; ++k) acc += sums[g * 128 + k] * Wl[k * OUTF + o];
    out[t] = acc * inv + bl[o];
}

extern "C" void kernel_launch(void* const* d_in, const int* in_sizes, int n_in,
                              void* d_out, int out_size, void* d_ws, size_t ws_size,
                              hipStream_t stream) {
    const float* x        = (const float*)d_in[0];
    const int*   ei       = (const int*)d_in[1];
    const int*   batch    = (const int*)d_in[2];
    const float* W1       = (const float*)d_in[3];
    const float* att_src1 = (const float*)d_in[4];
    const float* att_dst1 = (const float*)d_in[5];
    const float* b1       = (const float*)d_in[6];
    const float* W2       = (const float*)d_in[7];
    const float* att_src2 = (const float*)d_in[8];
    const float* att_dst2 = (const float*)d_in[9];
    const float* b2       = (const float*)d_in[10];
    const float* Wl       = (const float*)d_in[11];
    const float* bl       = (const float*)d_in[12];
    float* out = (float*)d_out;

    size_t off = 0;
    auto alloc = [&](size_t bytes) -> void* {
        void* p = (char*)d_ws + off;
        off = (off + bytes + 255) & ~(size_t)255;
        return p;
    };
    float*  A      = (float*)alloc((size_t)N_NODES * 128 * 4);
    float*  B      = (float*)alloc((size_t)N_NODES * 128 * 4);
    float2* a_src  = (float2*)alloc((size_t)N_NODES * 8);
    float2* a_dst  = (float2*)alloc((size_t)N_NODES * 8);
    int*    deg    = (int*)alloc((size_t)N_NODES * 4);
    int*    fill   = (int*)alloc((size_t)N_NODES * 4);
    int*    tmp    = (int*)alloc((size_t)N_NODES * 4);
    int*    bsum   = (int*)alloc(256 * 4);
    int*    rowptr = (int*)alloc((size_t)(N_NODES + 1) * 4);
    int*    csr    = (int*)alloc((size_t)ETOT * 4);
    float*  sums   = (float*)alloc((size_t)GRAPHS * HC * 4);
    int*    cnt    = (int*)alloc(GRAPHS * 4);

    const int nbN = (N_NODES + 255) / 256;      // 196

    // ---- CSR build (shared by both layers) ----
    initk<<<nbN, 256, 0, stream>>>(deg, fill, sums);
    degk<<<(N_EDGES + 255) / 256, 256, 0, stream>>>(ei, deg);
    scan1<<<nbN, 256, 0, stream>>>(deg, tmp, bsum);
    scan2<<<1, 256, 0, stream>>>(bsum, nbN);
    scan3<<<nbN, 256, 0, stream>>>(tmp, bsum, rowptr);
    fillk<<<(ETOT + 255) / 256, 256, 0, stream>>>(ei, rowptr, fill, csr);

    const int gemmBlocks = N_NODES / 8;          // 6250, exact
    const int waveBlocks = (N_NODES * 64 + 255) / 256;   // 12500

    // ---- layer 1 ----
    gemm128att<<<gemmBlocks, 256, 0, stream>>>(x, W1, att_src1, att_dst1, A, a_src, a_dst);
    aggk<<<waveBlocks, 256, 0, stream>>>(A, a_src, a_dst, rowptr, csr, b1, B);

    // ---- layer 2 ----
    gemm128att<<<gemmBlocks, 256, 0, stream>>>(B, W2, att_src2, att_dst2, A, a_src, a_dst);
    aggk<<<waveBlocks, 256, 0, stream>>>(A, a_src, a_dst, rowptr, csr, b2, B);

    // ---- pool + final linear ----
    countk<<<1, 64, 0, stream>>>(batch, cnt);
    poolk<<<(N_NODES + 63) / 64, 128, 0, stream>>>(B, batch, sums);
    finalk<<<1, 640, 0, stream>>>(sums, cnt, Wl, bl, out);
}

// Round 3
// 446.024 us; speedup vs baseline: 1.7589x; 1.2168x over previous
//
#include <hip/hip_runtime.h>
#include <math.h>

#define N_NODES 50000
#define N_EDGES 800000
#define ETOT    850000   // N_EDGES + N_NODES self-loops
#define GRAPHS  64
#define FIN     128
#define HC      128      // HEADS*HID
#define OUTF    10
#define NEG     0.2f

// ---------------- init ----------------
__global__ void initk(int* deg, int* fill, float* sums) {
    int i = blockIdx.x * 256 + threadIdx.x;
    if (i < N_NODES) { deg[i] = 1; fill[i] = 0; }   // deg starts at 1: self-loop
    if (i < GRAPHS * HC) sums[i] = 0.f;
}

// ---------------- degree count (real edges only) ----------------
__global__ void degk(const int* __restrict__ ei, int* deg) {
    int e = blockIdx.x * 256 + threadIdx.x;
    if (e < N_EDGES) atomicAdd(&deg[ei[N_EDGES + e]], 1);
}

// ---------------- 3-kernel exclusive scan over deg -> rowptr ----------------
__global__ void scan1(const int* __restrict__ deg, int* tmp, int* bsum) {
    __shared__ int sh[256];
    int t = threadIdx.x;
    int i = blockIdx.x * 256 + t;
    int v = (i < N_NODES) ? deg[i] : 0;
    sh[t] = v;
    __syncthreads();
    for (int off = 1; off < 256; off <<= 1) {
        int add = (t >= off) ? sh[t - off] : 0;
        __syncthreads();
        sh[t] += add;
        __syncthreads();
    }
    if (i < N_NODES) tmp[i] = sh[t];
    if (t == 255) bsum[blockIdx.x] = sh[255];
}

__global__ void scan2(int* bsum, int nb) {
    __shared__ int sh[256];
    int t = threadIdx.x;
    int v = (t < nb) ? bsum[t] : 0;
    sh[t] = v;
    __syncthreads();
    for (int off = 1; off < 256; off <<= 1) {
        int add = (t >= off) ? sh[t - off] : 0;
        __syncthreads();
        sh[t] += add;
        __syncthreads();
    }
    if (t < nb) bsum[t] = sh[t] - v;   // exclusive
}

__global__ void scan3(const int* __restrict__ tmp, const int* __restrict__ bsum, int* rowptr) {
    int i = blockIdx.x * 256 + threadIdx.x;
    if (i < N_NODES) rowptr[i + 1] = tmp[i] + bsum[blockIdx.x];
    if (i == 0) rowptr[0] = 0;
}

// ---------------- CSR fill (incl. self-loops) ----------------
__global__ void fillk(const int* __restrict__ ei, const int* __restrict__ rowptr,
                      int* fill, int* csr) {
    int e = blockIdx.x * 256 + threadIdx.x;
    if (e >= ETOT) return;
    int s, d;
    if (e < N_EDGES) { s = ei[e]; d = ei[N_EDGES + e]; }
    else             { s = d = e - N_EDGES; }
    int pos = rowptr[d] + atomicAdd(&fill[d], 1);
    csr[pos] = s;
}

// ---------------- GEMM + fused attention scores ----------------
// Y[M,128] = X[M,128] @ W[128,128]; a_src/a_dst per row from epilogue regs
__global__ __launch_bounds__(256) void gemm128att(const float* __restrict__ X,
                                                  const float* __restrict__ W,
                                                  const float* __restrict__ att_s,
                                                  const float* __restrict__ att_d,
                                                  float* __restrict__ Y,
                                                  float2* __restrict__ a_src,
                                                  float2* __restrict__ a_dst) {
    __shared__ float xs[8][128];
    int t = threadIdx.x;
    int r0 = blockIdx.x * 8;
    {
        int idx = t * 4;
        int rr = idx >> 7, cc = idx & 127;
        *(float4*)&xs[rr][cc] = *(const float4*)&X[(size_t)(r0 + rr) * 128 + cc];
    }
    __syncthreads();
    int r = t >> 5;
    int c4 = (t & 31) * 4;
    float4 acc = {0.f, 0.f, 0.f, 0.f};
#pragma unroll 8
    for (int k = 0; k < 128; ++k) {
        float xv = xs[r][k];
        float4 wv = *(const float4*)&W[k * 128 + c4];
        acc.x += xv * wv.x; acc.y += xv * wv.y;
        acc.z += xv * wv.z; acc.w += xv * wv.w;
    }
    *(float4*)&Y[(size_t)(r0 + r) * 128 + c4] = acc;

    // fused attention scores: row-group = 32 lanes; head0 = group-lanes 0-15,
    // head1 = group-lanes 16-31 (c4 >= 64)
    float4 sv = *(const float4*)&att_s[c4];
    float4 dv = *(const float4*)&att_d[c4];
    float ps = acc.x * sv.x + acc.y * sv.y + acc.z * sv.z + acc.w * sv.w;
    float pd = acc.x * dv.x + acc.y * dv.y + acc.z * dv.z + acc.w * dv.w;
    for (int off = 1; off < 16; off <<= 1) {
        ps += __shfl_xor(ps, off);
        pd += __shfl_xor(pd, off);
    }
    int lane = t & 63;
    float ps1 = __shfl(ps, (lane & 32) + 16);   // head1 sum lives at group-lane 16
    float pd1 = __shfl(pd, (lane & 32) + 16);
    if ((lane & 31) == 0) {
        a_src[r0 + r] = make_float2(ps, ps1);
        a_dst[r0 + r] = make_float2(pd, pd1);
    }
}

__device__ __forceinline__ float leaky(float x) { return x > 0.f ? x : NEG * x; }

// ---------------- softmax + aggregation: one wave per dst node ----------------
// Single pass (no max-shift needed in fp32: |alpha| <~ 7, exp bounded).
// Half-wave 0 handles even edges, half-wave 1 odd edges; each lane owns
// 4 features (float4). Final __shfl_xor(32) merges the two halves.
__global__ __launch_bounds__(256) void aggk(const float* __restrict__ H,
                                            const float2* __restrict__ a_src,
                                            const float2* __restrict__ a_dst,
                                            const int* __restrict__ rowptr,
                                            const int* __restrict__ csr,
                                            const float* __restrict__ bias,
                                            float* __restrict__ outp) {
    int wid = (blockIdx.x * 256 + threadIdx.x) >> 6;
    int lane = threadIdx.x & 63;
    if (wid >= N_NODES) return;
    int rbeg = rowptr[wid], rend = rowptr[wid + 1];
    float2 ad = a_dst[wid];

    int half = lane >> 5;       // which half-wave
    int hl   = lane & 31;       // lane within half: features f..f+3
    int head = hl >> 4;
    float adh = head ? ad.y : ad.x;
    int f = hl * 4;

    float4 acc = {0.f, 0.f, 0.f, 0.f};
    float denom = 0.f;
#pragma unroll 2
    for (int j = rbeg + half; j < rend; j += 2) {
        int s = csr[j];
        float2 as = a_src[s];
        float w = __expf(leaky((head ? as.y : as.x) + adh));
        float4 hv = *(const float4*)&H[(size_t)s * 128 + f];
        acc.x += w * hv.x; acc.y += w * hv.y;
        acc.z += w * hv.z; acc.w += w * hv.w;
        denom += w;
    }
    acc.x += __shfl_xor(acc.x, 32);
    acc.y += __shfl_xor(acc.y, 32);
    acc.z += __shfl_xor(acc.z, 32);
    acc.w += __shfl_xor(acc.w, 32);
    denom += __shfl_xor(denom, 32);

    if (half == 0) {
        float inv = 1.f / (denom + 1e-16f);
        float4 bb = *(const float4*)&bias[f];
        float4 o;
        o.x = fmaxf(acc.x * inv + bb.x, 0.f);
        o.y = fmaxf(acc.y * inv + bb.y, 0.f);
        o.z = fmaxf(acc.z * inv + bb.z, 0.f);
        o.w = fmaxf(acc.w * inv + bb.w, 0.f);
        *(float4*)&outp[(size_t)wid * 128 + f] = o;
    }
}

// ---------------- pooling ----------------
// batch is sorted: count via binary search, no atomics.
__global__ void countk(const int* __restrict__ batch, int* cnt) {
    int g = threadIdx.x;
    if (g >= GRAPHS) return;
    int lo = 0, hi = N_NODES;
    while (lo < hi) { int mid = (lo + hi) >> 1; if (batch[mid] < g) lo = mid + 1; else hi = mid; }
    int lb = lo;
    lo = 0; hi = N_NODES;
    while (lo < hi) { int mid = (lo + hi) >> 1; if (batch[mid] < g + 1) lo = mid + 1; else hi = mid; }
    cnt[g] = lo - lb;
}

__global__ void poolk(const float* __restrict__ H, const int* __restrict__ batch,
                      float* __restrict__ sums) {
    int f = threadIdx.x;            // 128 threads
    int n0 = blockIdx.x * 64;
    if (n0 >= N_NODES) return;
    int n1 = min(n0 + 64, N_NODES);
    int g = batch[n0];
    float run = 0.f;
    for (int n = n0; n < n1; ++n) {
        int gn = batch[n];
        if (gn != g) { atomicAdd(&sums[g * 128 + f], run); run = 0.f; g = gn; }
        run += H[(size_t)n * 128 + f];
    }
    atomicAdd(&sums[g * 128 + f], run);
}

__global__ void finalk(const float* __restrict__ sums, const int* __restrict__ cnt,
                       const float* __restrict__ Wl, const float* __restrict__ bl,
                       float* __restrict__ out) {
    int t = threadIdx.x;
    if (t >= GRAPHS * OUTF) return;
    int g = t / OUTF, o = t % OUTF;
    float inv = 1.f / fmaxf((float)cnt[g], 1.f);
    float acc = 0.f;
#pragma unroll 8
    for (int k = 0; k < 128; ++k) acc += sums[g * 128 + k] * Wl[k * OUTF + o];
    out[t] = acc * inv + bl[o];
}

extern "C" void kernel_launch(void* const* d_in, const int* in_sizes, int n_in,
                              void* d_out, int out_size, void* d_ws, size_t ws_size,
                              hipStream_t stream) {
    const float* x        = (const float*)d_in[0];
    const int*   ei       = (const int*)d_in[1];
    const int*   batch    = (const int*)d_in[2];
    const float* W1       = (const float*)d_in[3];
    const float* att_src1 = (const float*)d_in[4];
    const float* att_dst1 = (const float*)d_in[5];
    const float* b1       = (const float*)d_in[6];
    const float* W2       = (const float*)d_in[7];
    const float* att_src2 = (const float*)d_in[8];
    const float* att_dst2 = (const float*)d_in[9];
    const float* b2       = (const float*)d_in[10];
    const float* Wl       = (const float*)d_in[11];
    const float* bl       = (const float*)d_in[12];
    float* out = (float*)d_out;

    size_t off = 0;
    auto alloc = [&](size_t bytes) -> void* {
        void* p = (char*)d_ws + off;
        off = (off + bytes + 255) & ~(size_t)255;
        return p;
    };
    float*  A      = (float*)alloc((size_t)N_NODES * 128 * 4);
    float*  B      = (float*)alloc((size_t)N_NODES * 128 * 4);
    float2* a_src  = (float2*)alloc((size_t)N_NODES * 8);
    float2* a_dst  = (float2*)alloc((size_t)N_NODES * 8);
    int*    deg    = (int*)alloc((size_t)N_NODES * 4);
    int*    fill   = (int*)alloc((size_t)N_NODES * 4);
    int*    tmp    = (int*)alloc((size_t)N_NODES * 4);
    int*    bsum   = (int*)alloc(256 * 4);
    int*    rowptr = (int*)alloc((size_t)(N_NODES + 1) * 4);
    int*    csr    = (int*)alloc((size_t)ETOT * 4);
    float*  sums   = (float*)alloc((size_t)GRAPHS * HC * 4);
    int*    cnt    = (int*)alloc(GRAPHS * 4);

    const int nbN = (N_NODES + 255) / 256;      // 196

    // ---- CSR build (shared by both layers) ----
    initk<<<nbN, 256, 0, stream>>>(deg, fill, sums);
    degk<<<(N_EDGES + 255) / 256, 256, 0, stream>>>(ei, deg);
    scan1<<<nbN, 256, 0, stream>>>(deg, tmp, bsum);
    scan2<<<1, 256, 0, stream>>>(bsum, nbN);
    scan3<<<nbN, 256, 0, stream>>>(tmp, bsum, rowptr);
    fillk<<<(ETOT + 255) / 256, 256, 0, stream>>>(ei, rowptr, fill, csr);

    const int gemmBlocks = N_NODES / 8;          // 6250, exact
    const int waveBlocks = (N_NODES * 64 + 255) / 256;   // 12500

    // ---- layer 1 ----
    gemm128att<<<gemmBlocks, 256, 0, stream>>>(x, W1, att_src1, att_dst1, A, a_src, a_dst);
    aggk<<<waveBlocks, 256, 0, stream>>>(A, a_src, a_dst, rowptr, csr, b1, B);

    // ---- layer 2 ----
    gemm128att<<<gemmBlocks, 256, 0, stream>>>(B, W2, att_src2, att_dst2, A, a_src, a_dst);
    aggk<<<waveBlocks, 256, 0, stream>>>(A, a_src, a_dst, rowptr, csr, b2, B);

    // ---- pool + final linear ----
    countk<<<1, 64, 0, stream>>>(batch, cnt);
    poolk<<<(N_NODES + 63) / 64, 128, 0, stream>>>(B, batch, sums);
    finalk<<<1, 640, 0, stream>>>(sums, cnt, Wl, bl, out);
}

// Round 4
// 325.072 us; speedup vs baseline: 2.4134x; 1.3721x over previous
//
#include <hip/hip_runtime.h>
#include <math.h>

#define N_NODES 50000
#define N_EDGES 800000
#define ETOT    850000   // N_EDGES + N_NODES self-loops
#define GRAPHS  64
#define FIN     128
#define HC      128      // HEADS*HID
#define OUTF    10
#define NEG     0.2f
#define MROWS   64       // rows per GEMM block

// ---------------- init ----------------
__global__ void initk(int* deg, int* fill, float* sums) {
    int i = blockIdx.x * 256 + threadIdx.x;
    if (i < N_NODES) { deg[i] = 1; fill[i] = 0; }   // deg starts at 1: self-loop
    if (i < GRAPHS * HC) sums[i] = 0.f;
}

// ---------------- degree count (real edges only) ----------------
__global__ void degk(const int* __restrict__ ei, int* deg) {
    int e = blockIdx.x * 256 + threadIdx.x;
    if (e < N_EDGES) atomicAdd(&deg[ei[N_EDGES + e]], 1);
}

// ---------------- 3-kernel exclusive scan over deg -> rowptr ----------------
__global__ void scan1(const int* __restrict__ deg, int* tmp, int* bsum) {
    __shared__ int sh[256];
    int t = threadIdx.x;
    int i = blockIdx.x * 256 + t;
    int v = (i < N_NODES) ? deg[i] : 0;
    sh[t] = v;
    __syncthreads();
    for (int off = 1; off < 256; off <<= 1) {
        int add = (t >= off) ? sh[t - off] : 0;
        __syncthreads();
        sh[t] += add;
        __syncthreads();
    }
    if (i < N_NODES) tmp[i] = sh[t];
    if (t == 255) bsum[blockIdx.x] = sh[255];
}

__global__ void scan2(int* bsum, int nb) {
    __shared__ int sh[256];
    int t = threadIdx.x;
    int v = (t < nb) ? bsum[t] : 0;
    sh[t] = v;
    __syncthreads();
    for (int off = 1; off < 256; off <<= 1) {
        int add = (t >= off) ? sh[t - off] : 0;
        __syncthreads();
        sh[t] += add;
        __syncthreads();
    }
    if (t < nb) bsum[t] = sh[t] - v;   // exclusive
}

__global__ void scan3(const int* __restrict__ tmp, const int* __restrict__ bsum, int* rowptr) {
    int i = blockIdx.x * 256 + threadIdx.x;
    if (i < N_NODES) rowptr[i + 1] = tmp[i] + bsum[blockIdx.x];
    if (i == 0) rowptr[0] = 0;
}

// ---------------- CSR fill (incl. self-loops) ----------------
__global__ void fillk(const int* __restrict__ ei, const int* __restrict__ rowptr,
                      int* fill, int* csr) {
    int e = blockIdx.x * 256 + threadIdx.x;
    if (e >= ETOT) return;
    int s, d;
    if (e < N_EDGES) { s = ei[e]; d = ei[N_EDGES + e]; }
    else             { s = d = e - N_EDGES; }
    int pos = rowptr[d] + atomicAdd(&fill[d], 1);
    csr[pos] = s;
}

// ---------------- GEMM + fused attention scores ----------------
// Y[M,128] = X[M,128] @ W[128,128]; both X-tile and W staged in LDS.
// 64 rows/block; thread t owns rows rg*8..rg*8+7 (rg=t>>5), cols c4..c4+3.
// W staged as two 64-row K-halves to stay within 64 KB LDS (2 blocks/CU).
__global__ __launch_bounds__(256, 4) void gemm128att(const float* __restrict__ X,
                                                     const float* __restrict__ W,
                                                     const float* __restrict__ att_s,
                                                     const float* __restrict__ att_d,
                                                     float* __restrict__ Y,
                                                     float2* __restrict__ a_src,
                                                     float2* __restrict__ a_dst) {
    __shared__ float xs[MROWS][128];   // 32 KB
    __shared__ float ws[64][128];      // 32 KB (one K-half of W)
    int t = threadIdx.x;
    int r0 = blockIdx.x * MROWS;

    // stage X tile (guarded, coalesced float4)
#pragma unroll
    for (int s = 0; s < 8; ++s) {
        int idx = s * 1024 + t * 4;
        int rr = idx >> 7, cc = idx & 127;
        float4 v = {0.f, 0.f, 0.f, 0.f};
        if (r0 + rr < N_NODES) v = *(const float4*)&X[(size_t)(r0 + rr) * 128 + cc];
        *(float4*)&xs[rr][cc] = v;
    }

    int rg = t >> 5;               // 0..7: row group
    int c4 = (t & 31) * 4;         // column strip
    float4 acc[8];
#pragma unroll
    for (int i = 0; i < 8; ++i) acc[i] = {0.f, 0.f, 0.f, 0.f};

    for (int h = 0; h < 2; ++h) {
        __syncthreads();           // xs ready (h=0) / prev compute done (h=1)
#pragma unroll
        for (int s = 0; s < 8; ++s) {
            int idx = s * 1024 + t * 4;
            int kk = idx >> 7, cc = idx & 127;
            *(float4*)&ws[kk][cc] = *(const float4*)&W[(size_t)(h * 64 + kk) * 128 + cc];
        }
        __syncthreads();
#pragma unroll 4
        for (int kk = 0; kk < 64; ++kk) {
            float4 wv = *(const float4*)&ws[kk][c4];
#pragma unroll
            for (int i = 0; i < 8; ++i) {
                float xv = xs[rg * 8 + i][h * 64 + kk];
                acc[i].x += xv * wv.x; acc[i].y += xv * wv.y;
                acc[i].z += xv * wv.z; acc[i].w += xv * wv.w;
            }
        }
    }

    // epilogue: store Y + fused attention scores per register row
    float4 sv = *(const float4*)&att_s[c4];
    float4 dv = *(const float4*)&att_d[c4];
    int lane = t & 63;
#pragma unroll
    for (int i = 0; i < 8; ++i) {
        int row = r0 + rg * 8 + i;
        bool ok = row < N_NODES;
        if (ok) *(float4*)&Y[(size_t)row * 128 + c4] = acc[i];
        float ps = acc[i].x * sv.x + acc[i].y * sv.y + acc[i].z * sv.z + acc[i].w * sv.w;
        float pd = acc[i].x * dv.x + acc[i].y * dv.y + acc[i].z * dv.z + acc[i].w * dv.w;
        for (int off = 1; off < 16; off <<= 1) {
            ps += __shfl_xor(ps, off);
            pd += __shfl_xor(pd, off);
        }
        float ps1 = __shfl(ps, (lane & 32) + 16);   // head1 sum at group-lane 16
        float pd1 = __shfl(pd, (lane & 32) + 16);
        if ((lane & 31) == 0 && ok) {
            a_src[row] = make_float2(ps, ps1);
            a_dst[row] = make_float2(pd, pd1);
        }
    }
}

__device__ __forceinline__ float leaky(float x) { return x > 0.f ? x : NEG * x; }

// ---------------- softmax + aggregation: one wave per dst node ----------------
// Single pass (no max-shift needed in fp32: |alpha| <~ 7, exp bounded).
// Half-wave 0 handles even edges, half-wave 1 odd edges; each lane owns
// 4 features (float4). Final __shfl_xor(32) merges the two halves.
__global__ __launch_bounds__(256) void aggk(const float* __restrict__ H,
                                            const float2* __restrict__ a_src,
                                            const float2* __restrict__ a_dst,
                                            const int* __restrict__ rowptr,
                                            const int* __restrict__ csr,
                                            const float* __restrict__ bias,
                                            float* __restrict__ outp) {
    int wid = (blockIdx.x * 256 + threadIdx.x) >> 6;
    int lane = threadIdx.x & 63;
    if (wid >= N_NODES) return;
    int rbeg = rowptr[wid], rend = rowptr[wid + 1];
    float2 ad = a_dst[wid];

    int half = lane >> 5;       // which half-wave
    int hl   = lane & 31;       // lane within half: features f..f+3
    int head = hl >> 4;
    float adh = head ? ad.y : ad.x;
    int f = hl * 4;

    float4 acc = {0.f, 0.f, 0.f, 0.f};
    float denom = 0.f;
#pragma unroll 2
    for (int j = rbeg + half; j < rend; j += 2) {
        int s = csr[j];
        float2 as = a_src[s];
        float w = __expf(leaky((head ? as.y : as.x) + adh));
        float4 hv = *(const float4*)&H[(size_t)s * 128 + f];
        acc.x += w * hv.x; acc.y += w * hv.y;
        acc.z += w * hv.z; acc.w += w * hv.w;
        denom += w;
    }
    acc.x += __shfl_xor(acc.x, 32);
    acc.y += __shfl_xor(acc.y, 32);
    acc.z += __shfl_xor(acc.z, 32);
    acc.w += __shfl_xor(acc.w, 32);
    denom += __shfl_xor(denom, 32);

    if (half == 0) {
        float inv = 1.f / (denom + 1e-16f);
        float4 bb = *(const float4*)&bias[f];
        float4 o;
        o.x = fmaxf(acc.x * inv + bb.x, 0.f);
        o.y = fmaxf(acc.y * inv + bb.y, 0.f);
        o.z = fmaxf(acc.z * inv + bb.z, 0.f);
        o.w = fmaxf(acc.w * inv + bb.w, 0.f);
        *(float4*)&outp[(size_t)wid * 128 + f] = o;
    }
}

// ---------------- pooling ----------------
// batch is sorted: count via binary search, no atomics.
__global__ void countk(const int* __restrict__ batch, int* cnt) {
    int g = threadIdx.x;
    if (g >= GRAPHS) return;
    int lo = 0, hi = N_NODES;
    while (lo < hi) { int mid = (lo + hi) >> 1; if (batch[mid] < g) lo = mid + 1; else hi = mid; }
    int lb = lo;
    lo = 0; hi = N_NODES;
    while (lo < hi) { int mid = (lo + hi) >> 1; if (batch[mid] < g + 1) lo = mid + 1; else hi = mid; }
    cnt[g] = lo - lb;
}

__global__ void poolk(const float* __restrict__ H, const int* __restrict__ batch,
                      float* __restrict__ sums) {
    int f = threadIdx.x;            // 128 threads
    int n0 = blockIdx.x * 64;
    if (n0 >= N_NODES) return;
    int n1 = min(n0 + 64, N_NODES);
    int g = batch[n0];
    float run = 0.f;
    for (int n = n0; n < n1; ++n) {
        int gn = batch[n];
        if (gn != g) { atomicAdd(&sums[g * 128 + f], run); run = 0.f; g = gn; }
        run += H[(size_t)n * 128 + f];
    }
    atomicAdd(&sums[g * 128 + f], run);
}

__global__ void finalk(const float* __restrict__ sums, const int* __restrict__ cnt,
                       const float* __restrict__ Wl, const float* __restrict__ bl,
                       float* __restrict__ out) {
    int t = threadIdx.x;
    if (t >= GRAPHS * OUTF) return;
    int g = t / OUTF, o = t % OUTF;
    float inv = 1.f / fmaxf((float)cnt[g], 1.f);
    float acc = 0.f;
#pragma unroll 8
    for (int k = 0; k < 128; ++k) acc += sums[g * 128 + k] * Wl[k * OUTF + o];
    out[t] = acc * inv + bl[o];
}

extern "C" void kernel_launch(void* const* d_in, const int* in_sizes, int n_in,
                              void* d_out, int out_size, void* d_ws, size_t ws_size,
                              hipStream_t stream) {
    const float* x        = (const float*)d_in[0];
    const int*   ei       = (const int*)d_in[1];
    const int*   batch    = (const int*)d_in[2];
    const float* W1       = (const float*)d_in[3];
    const float* att_src1 = (const float*)d_in[4];
    const float* att_dst1 = (const float*)d_in[5];
    const float* b1       = (const float*)d_in[6];
    const float* W2       = (const float*)d_in[7];
    const float* att_src2 = (const float*)d_in[8];
    const float* att_dst2 = (const float*)d_in[9];
    const float* b2       = (const float*)d_in[10];
    const float* Wl       = (const float*)d_in[11];
    const float* bl       = (const float*)d_in[12];
    float* out = (float*)d_out;

    size_t off = 0;
    auto alloc = [&](size_t bytes) -> void* {
        void* p = (char*)d_ws + off;
        off = (off + bytes + 255) & ~(size_t)255;
        return p;
    };
    float*  A      = (float*)alloc((size_t)N_NODES * 128 * 4);
    float*  B      = (float*)alloc((size_t)N_NODES * 128 * 4);
    float2* a_src  = (float2*)alloc((size_t)N_NODES * 8);
    float2* a_dst  = (float2*)alloc((size_t)N_NODES * 8);
    int*    deg    = (int*)alloc((size_t)N_NODES * 4);
    int*    fill   = (int*)alloc((size_t)N_NODES * 4);
    int*    tmp    = (int*)alloc((size_t)N_NODES * 4);
    int*    bsum   = (int*)alloc(256 * 4);
    int*    rowptr = (int*)alloc((size_t)(N_NODES + 1) * 4);
    int*    csr    = (int*)alloc((size_t)ETOT * 4);
    float*  sums   = (float*)alloc((size_t)GRAPHS * HC * 4);
    int*    cnt    = (int*)alloc(GRAPHS * 4);

    const int nbN = (N_NODES + 255) / 256;      // 196

    // ---- CSR build (shared by both layers) ----
    initk<<<nbN, 256, 0, stream>>>(deg, fill, sums);
    degk<<<(N_EDGES + 255) / 256, 256, 0, stream>>>(ei, deg);
    scan1<<<nbN, 256, 0, stream>>>(deg, tmp, bsum);
    scan2<<<1, 256, 0, stream>>>(bsum, nbN);
    scan3<<<nbN, 256, 0, stream>>>(tmp, bsum, rowptr);
    fillk<<<(ETOT + 255) / 256, 256, 0, stream>>>(ei, rowptr, fill, csr);

    const int gemmBlocks = (N_NODES + MROWS - 1) / MROWS;   // 782
    const int waveBlocks = (N_NODES * 64 + 255) / 256;      // 12500

    // ---- layer 1 ----
    gemm128att<<<gemmBlocks, 256, 0, stream>>>(x, W1, att_src1, att_dst1, A, a_src, a_dst);
    aggk<<<waveBlocks, 256, 0, stream>>>(A, a_src, a_dst, rowptr, csr, b1, B);

    // ---- layer 2 ----
    gemm128att<<<gemmBlocks, 256, 0, stream>>>(B, W2, att_src2, att_dst2, A, a_src, a_dst);
    aggk<<<waveBlocks, 256, 0, stream>>>(A, a_src, a_dst, rowptr, csr, b2, B);

    // ---- pool + final linear ----
    countk<<<1, 64, 0, stream>>>(batch, cnt);
    poolk<<<(N_NODES + 63) / 64, 128, 0, stream>>>(B, batch, sums);
    finalk<<<1, 640, 0, stream>>>(sums, cnt, Wl, bl, out);
}

// Round 5
// 285.328 us; speedup vs baseline: 2.7495x; 1.1393x over previous
//
#include <hip/hip_runtime.h>
#include <hip/hip_fp16.h>
#include <math.h>

#define N_NODES 50000
#define N_EDGES 800000
#define ETOT    850000   // N_EDGES + N_NODES self-loops
#define GRAPHS  64
#define FIN     128
#define HC      128      // HEADS*HID
#define OUTF    10
#define NEG     0.2f
#define MROWS   64       // rows per GEMM block

// ---------------- init ----------------
__global__ void initk(int* deg, int* fill, float* sums) {
    int i = blockIdx.x * 256 + threadIdx.x;
    if (i < N_NODES) { deg[i] = 1; fill[i] = 0; }   // deg starts at 1: self-loop
    if (i < GRAPHS * HC) sums[i] = 0.f;
}

// ---------------- degree count (real edges only) ----------------
__global__ void degk(const int* __restrict__ ei, int* deg) {
    int e = blockIdx.x * 256 + threadIdx.x;
    if (e < N_EDGES) atomicAdd(&deg[ei[N_EDGES + e]], 1);
}

// ---------------- 3-kernel exclusive scan over deg -> rowptr ----------------
__global__ void scan1(const int* __restrict__ deg, int* tmp, int* bsum) {
    __shared__ int sh[256];
    int t = threadIdx.x;
    int i = blockIdx.x * 256 + t;
    int v = (i < N_NODES) ? deg[i] : 0;
    sh[t] = v;
    __syncthreads();
    for (int off = 1; off < 256; off <<= 1) {
        int add = (t >= off) ? sh[t - off] : 0;
        __syncthreads();
        sh[t] += add;
        __syncthreads();
    }
    if (i < N_NODES) tmp[i] = sh[t];
    if (t == 255) bsum[blockIdx.x] = sh[255];
}

__global__ void scan2(int* bsum, int nb) {
    __shared__ int sh[256];
    int t = threadIdx.x;
    int v = (t < nb) ? bsum[t] : 0;
    sh[t] = v;
    __syncthreads();
    for (int off = 1; off < 256; off <<= 1) {
        int add = (t >= off) ? sh[t - off] : 0;
        __syncthreads();
        sh[t] += add;
        __syncthreads();
    }
    if (t < nb) bsum[t] = sh[t] - v;   // exclusive
}

__global__ void scan3(const int* __restrict__ tmp, const int* __restrict__ bsum, int* rowptr) {
    int i = blockIdx.x * 256 + threadIdx.x;
    if (i < N_NODES) rowptr[i + 1] = tmp[i] + bsum[blockIdx.x];
    if (i == 0) rowptr[0] = 0;
}

// ---------------- CSR fill (incl. self-loops) ----------------
__global__ void fillk(const int* __restrict__ ei, const int* __restrict__ rowptr,
                      int* fill, int* csr) {
    int e = blockIdx.x * 256 + threadIdx.x;
    if (e >= ETOT) return;
    int s, d;
    if (e < N_EDGES) { s = ei[e]; d = ei[N_EDGES + e]; }
    else             { s = d = e - N_EDGES; }
    int pos = rowptr[d] + atomicAdd(&fill[d], 1);
    csr[pos] = s;
}

// ---------------- GEMM + fused attention scores + fp16 copy ----------------
// Y[M,128] = X[M,128] @ W[128,128]; both X-tile and W staged in LDS.
// 64 rows/block; thread t owns rows rg*8..rg*8+7 (rg=t>>5), cols c4..c4+3.
// Epilogue also writes H16 (packed fp16 copy of Y) for the gather kernel.
__global__ __launch_bounds__(256, 4) void gemm128att(const float* __restrict__ X,
                                                     const float* __restrict__ W,
                                                     const float* __restrict__ att_s,
                                                     const float* __restrict__ att_d,
                                                     float* __restrict__ Y,
                                                     __half* __restrict__ H16,
                                                     float2* __restrict__ a_src,
                                                     float2* __restrict__ a_dst) {
    __shared__ float xs[MROWS][128];   // 32 KB
    __shared__ float ws[64][128];      // 32 KB (one K-half of W)
    int t = threadIdx.x;
    int r0 = blockIdx.x * MROWS;

    // stage X tile (guarded, coalesced float4)
#pragma unroll
    for (int s = 0; s < 8; ++s) {
        int idx = s * 1024 + t * 4;
        int rr = idx >> 7, cc = idx & 127;
        float4 v = {0.f, 0.f, 0.f, 0.f};
        if (r0 + rr < N_NODES) v = *(const float4*)&X[(size_t)(r0 + rr) * 128 + cc];
        *(float4*)&xs[rr][cc] = v;
    }

    int rg = t >> 5;               // 0..7: row group
    int c4 = (t & 31) * 4;         // column strip
    float4 acc[8];
#pragma unroll
    for (int i = 0; i < 8; ++i) acc[i] = {0.f, 0.f, 0.f, 0.f};

    for (int h = 0; h < 2; ++h) {
        __syncthreads();           // xs ready (h=0) / prev compute done (h=1)
#pragma unroll
        for (int s = 0; s < 8; ++s) {
            int idx = s * 1024 + t * 4;
            int kk = idx >> 7, cc = idx & 127;
            *(float4*)&ws[kk][cc] = *(const float4*)&W[(size_t)(h * 64 + kk) * 128 + cc];
        }
        __syncthreads();
#pragma unroll 4
        for (int kk = 0; kk < 64; ++kk) {
            float4 wv = *(const float4*)&ws[kk][c4];
#pragma unroll
            for (int i = 0; i < 8; ++i) {
                float xv = xs[rg * 8 + i][h * 64 + kk];
                acc[i].x += xv * wv.x; acc[i].y += xv * wv.y;
                acc[i].z += xv * wv.z; acc[i].w += xv * wv.w;
            }
        }
    }

    // epilogue: store Y (fp32) + H16 (fp16) + fused attention scores
    float4 sv = *(const float4*)&att_s[c4];
    float4 dv = *(const float4*)&att_d[c4];
    int lane = t & 63;
#pragma unroll
    for (int i = 0; i < 8; ++i) {
        int row = r0 + rg * 8 + i;
        bool ok = row < N_NODES;
        if (ok) {
            *(float4*)&Y[(size_t)row * 128 + c4] = acc[i];
            __half2 p0 = __floats2half2_rn(acc[i].x, acc[i].y);
            __half2 p1 = __floats2half2_rn(acc[i].z, acc[i].w);
            uint2 pk;
            pk.x = *(unsigned int*)&p0;
            pk.y = *(unsigned int*)&p1;
            *(uint2*)&H16[(size_t)row * 128 + c4] = pk;
        }
        float ps = acc[i].x * sv.x + acc[i].y * sv.y + acc[i].z * sv.z + acc[i].w * sv.w;
        float pd = acc[i].x * dv.x + acc[i].y * dv.y + acc[i].z * dv.z + acc[i].w * dv.w;
        for (int off = 1; off < 16; off <<= 1) {
            ps += __shfl_xor(ps, off);
            pd += __shfl_xor(pd, off);
        }
        float ps1 = __shfl(ps, (lane & 32) + 16);   // head1 sum at group-lane 16
        float pd1 = __shfl(pd, (lane & 32) + 16);
        if ((lane & 31) == 0 && ok) {
            a_src[row] = make_float2(ps, ps1);
            a_dst[row] = make_float2(pd, pd1);
        }
    }
}

__device__ __forceinline__ float leaky(float x) { return x > 0.f ? x : NEG * x; }

// ---------------- softmax + aggregation: one wave per dst node ----------------
// Single pass, fp16 gather. Wave = 4 groups of 16 lanes; group g handles
// edges j = rbeg+g, j += 4 (4 gather chains in flight). Each lane owns 8
// features (16 B fp16 load). Final reduce across groups via shfl_xor 16,32.
__global__ __launch_bounds__(256) void aggk(const __half* __restrict__ H16,
                                            const float2* __restrict__ a_src,
                                            const float2* __restrict__ a_dst,
                                            const int* __restrict__ rowptr,
                                            const int* __restrict__ csr,
                                            const float* __restrict__ bias,
                                            float* __restrict__ outp) {
    int wid = (blockIdx.x * 256 + threadIdx.x) >> 6;
    int lane = threadIdx.x & 63;
    if (wid >= N_NODES) return;
    int rbeg = rowptr[wid], rend = rowptr[wid + 1];
    float2 ad = a_dst[wid];

    int grp = lane >> 4;        // 0..3
    int gl  = lane & 15;        // lane within group: features gl*8..+7
    int head = gl >> 3;         // gl<8 -> head0 (f<64), else head1
    float adh = head ? ad.y : ad.x;
    int f = gl * 8;

    float acc[8] = {0.f, 0.f, 0.f, 0.f, 0.f, 0.f, 0.f, 0.f};
    float denom = 0.f;
#pragma unroll 2
    for (int j = rbeg + grp; j < rend; j += 4) {
        int s = csr[j];
        float2 as = a_src[s];
        float w = __expf(leaky((head ? as.y : as.x) + adh));
        uint4 raw = *(const uint4*)&H16[(size_t)s * 128 + f];
        float2 f0 = __half22float2(*(__half2*)&raw.x);
        float2 f1 = __half22float2(*(__half2*)&raw.y);
        float2 f2 = __half22float2(*(__half2*)&raw.z);
        float2 f3 = __half22float2(*(__half2*)&raw.w);
        acc[0] += w * f0.x; acc[1] += w * f0.y;
        acc[2] += w * f1.x; acc[3] += w * f1.y;
        acc[4] += w * f2.x; acc[5] += w * f2.y;
        acc[6] += w * f3.x; acc[7] += w * f3.y;
        denom += w;
    }
    // reduce across the 4 groups (lanes differing in bits 4,5)
#pragma unroll
    for (int off = 16; off <= 32; off <<= 1) {
#pragma unroll
        for (int i = 0; i < 8; ++i) acc[i] += __shfl_xor(acc[i], off);
        denom += __shfl_xor(denom, off);
    }

    if (grp == 0) {
        float inv = 1.f / (denom + 1e-16f);
        float4 bb0 = *(const float4*)&bias[f];
        float4 bb1 = *(const float4*)&bias[f + 4];
        float4 o0, o1;
        o0.x = fmaxf(acc[0] * inv + bb0.x, 0.f);
        o0.y = fmaxf(acc[1] * inv + bb0.y, 0.f);
        o0.z = fmaxf(acc[2] * inv + bb0.z, 0.f);
        o0.w = fmaxf(acc[3] * inv + bb0.w, 0.f);
        o1.x = fmaxf(acc[4] * inv + bb1.x, 0.f);
        o1.y = fmaxf(acc[5] * inv + bb1.y, 0.f);
        o1.z = fmaxf(acc[6] * inv + bb1.z, 0.f);
        o1.w = fmaxf(acc[7] * inv + bb1.w, 0.f);
        *(float4*)&outp[(size_t)wid * 128 + f] = o0;
        *(float4*)&outp[(size_t)wid * 128 + f + 4] = o1;
    }
}

// ---------------- pooling ----------------
// batch is sorted: count via binary search, no atomics.
__global__ void countk(const int* __restrict__ batch, int* cnt) {
    int g = threadIdx.x;
    if (g >= GRAPHS) return;
    int lo = 0, hi = N_NODES;
    while (lo < hi) { int mid = (lo + hi) >> 1; if (batch[mid] < g) lo = mid + 1; else hi = mid; }
    int lb = lo;
    lo = 0; hi = N_NODES;
    while (lo < hi) { int mid = (lo + hi) >> 1; if (batch[mid] < g + 1) lo = mid + 1; else hi = mid; }
    cnt[g] = lo - lb;
}

__global__ void poolk(const float* __restrict__ H, const int* __restrict__ batch,
                      float* __restrict__ sums) {
    int f = threadIdx.x;            // 128 threads
    int n0 = blockIdx.x * 64;
    if (n0 >= N_NODES) return;
    int n1 = min(n0 + 64, N_NODES);
    int g = batch[n0];
    float run = 0.f;
    for (int n = n0; n < n1; ++n) {
        int gn = batch[n];
        if (gn != g) { atomicAdd(&sums[g * 128 + f], run); run = 0.f; g = gn; }
        run += H[(size_t)n * 128 + f];
    }
    atomicAdd(&sums[g * 128 + f], run);
}

__global__ void finalk(const float* __restrict__ sums, const int* __restrict__ cnt,
                       const float* __restrict__ Wl, const float* __restrict__ bl,
                       float* __restrict__ out) {
    int t = threadIdx.x;
    if (t >= GRAPHS * OUTF) return;
    int g = t / OUTF, o = t % OUTF;
    float inv = 1.f / fmaxf((float)cnt[g], 1.f);
    float acc = 0.f;
#pragma unroll 8
    for (int k = 0; k < 128; ++k) acc += sums[g * 128 + k] * Wl[k * OUTF + o];
    out[t] = acc * inv + bl[o];
}

extern "C" void kernel_launch(void* const* d_in, const int* in_sizes, int n_in,
                              void* d_out, int out_size, void* d_ws, size_t ws_size,
                              hipStream_t stream) {
    const float* x        = (const float*)d_in[0];
    const int*   ei       = (const int*)d_in[1];
    const int*   batch    = (const int*)d_in[2];
    const float* W1       = (const float*)d_in[3];
    const float* att_src1 = (const float*)d_in[4];
    const float* att_dst1 = (const float*)d_in[5];
    const float* b1       = (const float*)d_in[6];
    const float* W2       = (const float*)d_in[7];
    const float* att_src2 = (const float*)d_in[8];
    const float* att_dst2 = (const float*)d_in[9];
    const float* b2       = (const float*)d_in[10];
    const float* Wl       = (const float*)d_in[11];
    const float* bl       = (const float*)d_in[12];
    float* out = (float*)d_out;

    size_t off = 0;
    auto alloc = [&](size_t bytes) -> void* {
        void* p = (char*)d_ws + off;
        off = (off + bytes + 255) & ~(size_t)255;
        return p;
    };
    float*  A      = (float*)alloc((size_t)N_NODES * 128 * 4);
    float*  B      = (float*)alloc((size_t)N_NODES * 128 * 4);
    __half* H16    = (__half*)alloc((size_t)N_NODES * 128 * 2);
    float2* a_src  = (float2*)alloc((size_t)N_NODES * 8);
    float2* a_dst  = (float2*)alloc((size_t)N_NODES * 8);
    int*    deg    = (int*)alloc((size_t)N_NODES * 4);
    int*    fill   = (int*)alloc((size_t)N_NODES * 4);
    int*    tmp    = (int*)alloc((size_t)N_NODES * 4);
    int*    bsum   = (int*)alloc(256 * 4);
    int*    rowptr = (int*)alloc((size_t)(N_NODES + 1) * 4);
    int*    csr    = (int*)alloc((size_t)ETOT * 4);
    float*  sums   = (float*)alloc((size_t)GRAPHS * HC * 4);
    int*    cnt    = (int*)alloc(GRAPHS * 4);

    const int nbN = (N_NODES + 255) / 256;      // 196

    // ---- CSR build (shared by both layers) ----
    initk<<<nbN, 256, 0, stream>>>(deg, fill, sums);
    degk<<<(N_EDGES + 255) / 256, 256, 0, stream>>>(ei, deg);
    scan1<<<nbN, 256, 0, stream>>>(deg, tmp, bsum);
    scan2<<<1, 256, 0, stream>>>(bsum, nbN);
    scan3<<<nbN, 256, 0, stream>>>(tmp, bsum, rowptr);
    fillk<<<(ETOT + 255) / 256, 256, 0, stream>>>(ei, rowptr, fill, csr);

    const int gemmBlocks = (N_NODES + MROWS - 1) / MROWS;   // 782
    const int waveBlocks = (N_NODES * 64 + 255) / 256;      // 12500

    // ---- layer 1 ----
    gemm128att<<<gemmBlocks, 256, 0, stream>>>(x, W1, att_src1, att_dst1, A, H16, a_src, a_dst);
    aggk<<<waveBlocks, 256, 0, stream>>>(H16, a_src, a_dst, rowptr, csr, b1, B);

    // ---- layer 2 ----
    gemm128att<<<gemmBlocks, 256, 0, stream>>>(B, W2, att_src2, att_dst2, A, H16, a_src, a_dst);
    aggk<<<waveBlocks, 256, 0, stream>>>(H16, a_src, a_dst, rowptr, csr, b2, B);

    // ---- pool + final linear ----
    countk<<<1, 64, 0, stream>>>(batch, cnt);
    poolk<<<(N_NODES + 63) / 64, 128, 0, stream>>>(B, batch, sums);
    finalk<<<1, 640, 0, stream>>>(sums, cnt, Wl, bl, out);
}

// Round 6
// 223.769 us; speedup vs baseline: 3.5059x; 1.2751x over previous
//
#include <hip/hip_runtime.h>
#include <hip/hip_fp16.h>
#include <math.h>

#define N_NODES 50000
#define N_EDGES 800000
#define ETOT    850000   // N_EDGES + N_NODES self-loops
#define GRAPHS  64
#define FIN     128
#define HC      128      // HEADS*HID
#define OUTF    10
#define NEG     0.2f
#define MROWS   64       // rows per GEMM block

#define NBUCK   196      // ceil(50000/256) buckets of 256 dst nodes
#define BCAP    8192     // slots per bucket (mean 4338, sigma ~66 -> safe)
#define EPT     8        // edges per thread in bucketA

// ---------------- init: zero bucket tails + pool sums ----------------
__global__ void initk(int* tails, float* sums) {
    int i = blockIdx.x * 256 + threadIdx.x;
    if (i < NBUCK) tails[i] = 0;
    if (i < GRAPHS * HC) sums[i] = 0.f;
}

// ---------------- bucketA: bin edges by dst bucket, dense-ish writes ----------------
__global__ __launch_bounds__(256) void bucketA(const int* __restrict__ ei,
                                               int* __restrict__ tails,
                                               int* __restrict__ bdata) {
    __shared__ int hist[NBUCK];
    __shared__ int lbase[NBUCK];
    int t = threadIdx.x;
    int e0 = blockIdx.x * (256 * EPT);
    for (int i = t; i < NBUCK; i += 256) hist[i] = 0;
    __syncthreads();

    int bb[EPT], pk[EPT], rk[EPT];
#pragma unroll
    for (int i = 0; i < EPT; ++i) {
        int e = e0 + i * 256 + t;
        bb[i] = -1;
        if (e < ETOT) {
            int s, d;
            if (e < N_EDGES) { s = ei[e]; d = ei[N_EDGES + e]; }
            else             { s = d = e - N_EDGES; }
            bb[i] = d >> 8;
            pk[i] = s | ((d & 255) << 16);       // src fits 16 bits (<65536)
            rk[i] = atomicAdd(&hist[bb[i]], 1);  // rank within (block, bucket)
        }
    }
    __syncthreads();
    for (int i = t; i < NBUCK; i += 256)
        lbase[i] = atomicAdd(&tails[i], hist[i]);   // reserve range per bucket
    __syncthreads();
#pragma unroll
    for (int i = 0; i < EPT; ++i)
        if (bb[i] >= 0) bdata[bb[i] * BCAP + lbase[bb[i]] + rk[i]] = pk[i];
}

// ---------------- scanBuckets: exclusive scan of bucket counts ----------------
__global__ void scanBuckets(const int* __restrict__ tails,
                            int* __restrict__ csrBase,
                            int* __restrict__ rowptr) {
    __shared__ int sh[256];
    int t = threadIdx.x;
    int c = (t < NBUCK) ? tails[t] : 0;
    sh[t] = c;
    __syncthreads();
    for (int off = 1; off < 256; off <<= 1) {
        int add = (t >= off) ? sh[t - off] : 0;
        __syncthreads();
        sh[t] += add;
        __syncthreads();
    }
    if (t < NBUCK) csrBase[t] = sh[t] - c;          // exclusive
    if (t == NBUCK - 1) rowptr[N_NODES] = sh[t];    // == ETOT
}

// ---------------- bucketB: per-bucket CSR fill, all writes dense ----------------
__global__ __launch_bounds__(256) void bucketB(const int* __restrict__ bdata,
                                               const int* __restrict__ tails,
                                               const int* __restrict__ csrBase,
                                               int* __restrict__ rowptr,
                                               int* __restrict__ csr) {
    __shared__ int hist[256];
    __shared__ int scanws[256];
    int b = blockIdx.x;
    int t = threadIdx.x;
    int nodes0 = b << 8;
    int nnodes = min(256, N_NODES - nodes0);
    int cnt  = tails[b];
    int base = csrBase[b];
    const int* bd = &bdata[b * BCAP];

    hist[t] = 0;
    __syncthreads();
    for (int j = t; j < cnt; j += 256) {
        int dloc = bd[j] >> 16;
        atomicAdd(&hist[dloc], 1);
    }
    __syncthreads();
    scanws[t] = hist[t];
    __syncthreads();
    for (int off = 1; off < 256; off <<= 1) {
        int add = (t >= off) ? scanws[t - off] : 0;
        __syncthreads();
        scanws[t] += add;
        __syncthreads();
    }
    int excl = scanws[t] - hist[t];
    if (t < nnodes) rowptr[nodes0 + t] = base + excl;
    __syncthreads();
    hist[t] = excl;              // becomes cursor
    __syncthreads();
    for (int j = t; j < cnt; j += 256) {
        int pkv = bd[j];
        int dloc = pkv >> 16;
        int pos = atomicAdd(&hist[dloc], 1);
        csr[base + pos] = pkv & 0xFFFF;
    }
}

// ---------------- GEMM + fused attention scores + fp16 copy ----------------
__global__ __launch_bounds__(256, 4) void gemm128att(const float* __restrict__ X,
                                                     const float* __restrict__ W,
                                                     const float* __restrict__ att_s,
                                                     const float* __restrict__ att_d,
                                                     float* __restrict__ Y,
                                                     __half* __restrict__ H16,
                                                     float2* __restrict__ a_src,
                                                     float2* __restrict__ a_dst) {
    __shared__ float xs[MROWS][128];   // 32 KB
    __shared__ float ws[64][128];      // 32 KB (one K-half of W)
    int t = threadIdx.x;
    int r0 = blockIdx.x * MROWS;

#pragma unroll
    for (int s = 0; s < 8; ++s) {
        int idx = s * 1024 + t * 4;
        int rr = idx >> 7, cc = idx & 127;
        float4 v = {0.f, 0.f, 0.f, 0.f};
        if (r0 + rr < N_NODES) v = *(const float4*)&X[(size_t)(r0 + rr) * 128 + cc];
        *(float4*)&xs[rr][cc] = v;
    }

    int rg = t >> 5;
    int c4 = (t & 31) * 4;
    float4 acc[8];
#pragma unroll
    for (int i = 0; i < 8; ++i) acc[i] = {0.f, 0.f, 0.f, 0.f};

    for (int h = 0; h < 2; ++h) {
        __syncthreads();
#pragma unroll
        for (int s = 0; s < 8; ++s) {
            int idx = s * 1024 + t * 4;
            int kk = idx >> 7, cc = idx & 127;
            *(float4*)&ws[kk][cc] = *(const float4*)&W[(size_t)(h * 64 + kk) * 128 + cc];
        }
        __syncthreads();
#pragma unroll 4
        for (int kk = 0; kk < 64; ++kk) {
            float4 wv = *(const float4*)&ws[kk][c4];
#pragma unroll
            for (int i = 0; i < 8; ++i) {
                float xv = xs[rg * 8 + i][h * 64 + kk];
                acc[i].x += xv * wv.x; acc[i].y += xv * wv.y;
                acc[i].z += xv * wv.z; acc[i].w += xv * wv.w;
            }
        }
    }

    float4 sv = *(const float4*)&att_s[c4];
    float4 dv = *(const float4*)&att_d[c4];
    int lane = t & 63;
#pragma unroll
    for (int i = 0; i < 8; ++i) {
        int row = r0 + rg * 8 + i;
        bool ok = row < N_NODES;
        if (ok) {
            *(float4*)&Y[(size_t)row * 128 + c4] = acc[i];
            __half2 p0 = __floats2half2_rn(acc[i].x, acc[i].y);
            __half2 p1 = __floats2half2_rn(acc[i].z, acc[i].w);
            uint2 pkv;
            pkv.x = *(unsigned int*)&p0;
            pkv.y = *(unsigned int*)&p1;
            *(uint2*)&H16[(size_t)row * 128 + c4] = pkv;
        }
        float ps = acc[i].x * sv.x + acc[i].y * sv.y + acc[i].z * sv.z + acc[i].w * sv.w;
        float pd = acc[i].x * dv.x + acc[i].y * dv.y + acc[i].z * dv.z + acc[i].w * dv.w;
        for (int off = 1; off < 16; off <<= 1) {
            ps += __shfl_xor(ps, off);
            pd += __shfl_xor(pd, off);
        }
        float ps1 = __shfl(ps, (lane & 32) + 16);
        float pd1 = __shfl(pd, (lane & 32) + 16);
        if ((lane & 31) == 0 && ok) {
            a_src[row] = make_float2(ps, ps1);
            a_dst[row] = make_float2(pd, pd1);
        }
    }
}

__device__ __forceinline__ float leaky(float x) { return x > 0.f ? x : NEG * x; }

// ---------------- softmax + aggregation: one wave per dst node ----------------
__global__ __launch_bounds__(256) void aggk(const __half* __restrict__ H16,
                                            const float2* __restrict__ a_src,
                                            const float2* __restrict__ a_dst,
                                            const int* __restrict__ rowptr,
                                            const int* __restrict__ csr,
                                            const float* __restrict__ bias,
                                            float* __restrict__ outp) {
    int wid = (blockIdx.x * 256 + threadIdx.x) >> 6;
    int lane = threadIdx.x & 63;
    if (wid >= N_NODES) return;
    int rbeg = rowptr[wid], rend = rowptr[wid + 1];
    float2 ad = a_dst[wid];

    int grp = lane >> 4;
    int gl  = lane & 15;
    int head = gl >> 3;
    float adh = head ? ad.y : ad.x;
    int f = gl * 8;

    float acc[8] = {0.f, 0.f, 0.f, 0.f, 0.f, 0.f, 0.f, 0.f};
    float denom = 0.f;
#pragma unroll 2
    for (int j = rbeg + grp; j < rend; j += 4) {
        int s = csr[j];
        float2 as = a_src[s];
        float w = __expf(leaky((head ? as.y : as.x) + adh));
        uint4 raw = *(const uint4*)&H16[(size_t)s * 128 + f];
        float2 f0 = __half22float2(*(__half2*)&raw.x);
        float2 f1 = __half22float2(*(__half2*)&raw.y);
        float2 f2 = __half22float2(*(__half2*)&raw.z);
        float2 f3 = __half22float2(*(__half2*)&raw.w);
        acc[0] += w * f0.x; acc[1] += w * f0.y;
        acc[2] += w * f1.x; acc[3] += w * f1.y;
        acc[4] += w * f2.x; acc[5] += w * f2.y;
        acc[6] += w * f3.x; acc[7] += w * f3.y;
        denom += w;
    }
#pragma unroll
    for (int off = 16; off <= 32; off <<= 1) {
#pragma unroll
        for (int i = 0; i < 8; ++i) acc[i] += __shfl_xor(acc[i], off);
        denom += __shfl_xor(denom, off);
    }

    if (grp == 0) {
        float inv = 1.f / (denom + 1e-16f);
        float4 bb0 = *(const float4*)&bias[f];
        float4 bb1 = *(const float4*)&bias[f + 4];
        float4 o0, o1;
        o0.x = fmaxf(acc[0] * inv + bb0.x, 0.f);
        o0.y = fmaxf(acc[1] * inv + bb0.y, 0.f);
        o0.z = fmaxf(acc[2] * inv + bb0.z, 0.f);
        o0.w = fmaxf(acc[3] * inv + bb0.w, 0.f);
        o1.x = fmaxf(acc[4] * inv + bb1.x, 0.f);
        o1.y = fmaxf(acc[5] * inv + bb1.y, 0.f);
        o1.z = fmaxf(acc[6] * inv + bb1.z, 0.f);
        o1.w = fmaxf(acc[7] * inv + bb1.w, 0.f);
        *(float4*)&outp[(size_t)wid * 128 + f] = o0;
        *(float4*)&outp[(size_t)wid * 128 + f + 4] = o1;
    }
}

// ---------------- pooling ----------------
__global__ void countk(const int* __restrict__ batch, int* cnt) {
    int g = threadIdx.x;
    if (g >= GRAPHS) return;
    int lo = 0, hi = N_NODES;
    while (lo < hi) { int mid = (lo + hi) >> 1; if (batch[mid] < g) lo = mid + 1; else hi = mid; }
    int lb = lo;
    lo = 0; hi = N_NODES;
    while (lo < hi) { int mid = (lo + hi) >> 1; if (batch[mid] < g + 1) lo = mid + 1; else hi = mid; }
    cnt[g] = lo - lb;
}

__global__ void poolk(const float* __restrict__ H, const int* __restrict__ batch,
                      float* __restrict__ sums) {
    int f = threadIdx.x;            // 128 threads
    int n0 = blockIdx.x * 64;
    if (n0 >= N_NODES) return;
    int n1 = min(n0 + 64, N_NODES);
    int g = batch[n0];
    float run = 0.f;
    for (int n = n0; n < n1; ++n) {
        int gn = batch[n];
        if (gn != g) { atomicAdd(&sums[g * 128 + f], run); run = 0.f; g = gn; }
        run += H[(size_t)n * 128 + f];
    }
    atomicAdd(&sums[g * 128 + f], run);
}

__global__ void finalk(const float* __restrict__ sums, const int* __restrict__ cnt,
                       const float* __restrict__ Wl, const float* __restrict__ bl,
                       float* __restrict__ out) {
    int t = threadIdx.x;
    if (t >= GRAPHS * OUTF) return;
    int g = t / OUTF, o = t % OUTF;
    float inv = 1.f / fmaxf((float)cnt[g], 1.f);
    float acc = 0.f;
#pragma unroll 8
    for (int k = 0; k < 128; ++k) acc += sums[g * 128 + k] * Wl[k * OUTF + o];
    out[t] = acc * inv + bl[o];
}

extern "C" void kernel_launch(void* const* d_in, const int* in_sizes, int n_in,
                              void* d_out, int out_size, void* d_ws, size_t ws_size,
                              hipStream_t stream) {
    const float* x        = (const float*)d_in[0];
    const int*   ei       = (const int*)d_in[1];
    const int*   batch    = (const int*)d_in[2];
    const float* W1       = (const float*)d_in[3];
    const float* att_src1 = (const float*)d_in[4];
    const float* att_dst1 = (const float*)d_in[5];
    const float* b1       = (const float*)d_in[6];
    const float* W2       = (const float*)d_in[7];
    const float* att_src2 = (const float*)d_in[8];
    const float* att_dst2 = (const float*)d_in[9];
    const float* b2       = (const float*)d_in[10];
    const float* Wl       = (const float*)d_in[11];
    const float* bl       = (const float*)d_in[12];
    float* out = (float*)d_out;

    size_t off = 0;
    auto alloc = [&](size_t bytes) -> void* {
        void* p = (char*)d_ws + off;
        off = (off + bytes + 255) & ~(size_t)255;
        return p;
    };
    float*  A       = (float*)alloc((size_t)N_NODES * 128 * 4);
    float*  B       = (float*)alloc((size_t)N_NODES * 128 * 4);
    __half* H16     = (__half*)alloc((size_t)N_NODES * 128 * 2);
    float2* a_src   = (float2*)alloc((size_t)N_NODES * 8);
    float2* a_dst   = (float2*)alloc((size_t)N_NODES * 8);
    int*    bdata   = (int*)alloc((size_t)NBUCK * BCAP * 4);
    int*    tails   = (int*)alloc(NBUCK * 4);
    int*    csrBase = (int*)alloc(NBUCK * 4);
    int*    rowptr  = (int*)alloc((size_t)(N_NODES + 1) * 4);
    int*    csr     = (int*)alloc((size_t)ETOT * 4);
    float*  sums    = (float*)alloc((size_t)GRAPHS * HC * 4);
    int*    cnt     = (int*)alloc(GRAPHS * 4);

    // ---- CSR build (dense-write bucket path) ----
    initk<<<32, 256, 0, stream>>>(tails, sums);
    bucketA<<<(ETOT + 2047) / 2048, 256, 0, stream>>>(ei, tails, bdata);
    scanBuckets<<<1, 256, 0, stream>>>(tails, csrBase, rowptr);
    bucketB<<<NBUCK, 256, 0, stream>>>(bdata, tails, csrBase, rowptr, csr);

    const int gemmBlocks = (N_NODES + MROWS - 1) / MROWS;   // 782
    const int waveBlocks = (N_NODES * 64 + 255) / 256;      // 12500

    // ---- layer 1 ----
    gemm128att<<<gemmBlocks, 256, 0, stream>>>(x, W1, att_src1, att_dst1, A, H16, a_src, a_dst);
    aggk<<<waveBlocks, 256, 0, stream>>>(H16, a_src, a_dst, rowptr, csr, b1, B);

    // ---- layer 2 ----
    gemm128att<<<gemmBlocks, 256, 0, stream>>>(B, W2, att_src2, att_dst2, A, H16, a_src, a_dst);
    aggk<<<waveBlocks, 256, 0, stream>>>(H16, a_src, a_dst, rowptr, csr, b2, B);

    // ---- pool + final linear ----
    countk<<<1, 64, 0, stream>>>(batch, cnt);
    poolk<<<(N_NODES + 63) / 64, 128, 0, stream>>>(B, batch, sums);
    finalk<<<1, 640, 0, stream>>>(sums, cnt, Wl, bl, out);
}

// Round 7
// 183.507 us; speedup vs baseline: 4.2752x; 1.2194x over previous
//
#include <hip/hip_runtime.h>
#include <hip/hip_fp16.h>
#include <math.h>

#define N_NODES 50000
#define N_EDGES 800000
#define ETOT    850000   // N_EDGES + N_NODES self-loops
#define GRAPHS  64
#define FIN     128
#define HC      128      // HEADS*HID
#define OUTF    10
#define NEG     0.2f

#define NBUCK   196      // ceil(50000/256) buckets of 256 dst nodes
#define BCAP    8192     // slots per bucket (mean 4338, sigma ~66 -> safe)
#define EPT     8        // edges per thread in bucketA

using half8  = __attribute__((ext_vector_type(8))) _Float16;
using float4v = __attribute__((ext_vector_type(4))) float;

// ---------------- init: zero bucket tails + pool sums ----------------
__global__ void initk(int* tails, float* sums) {
    int i = blockIdx.x * 256 + threadIdx.x;
    if (i < NBUCK) tails[i] = 0;
    if (i < GRAPHS * HC) sums[i] = 0.f;
}

// ---------------- W -> fp16 transposed copies ----------------
__global__ void wconv(const float* __restrict__ W1, const float* __restrict__ W2,
                      _Float16* __restrict__ WT1, _Float16* __restrict__ WT2) {
    int t = blockIdx.x * 256 + threadIdx.x;
    if (t < 16384) {
        int n = t >> 7, k = t & 127;          // output index WT[n][k]
        WT1[t] = (_Float16)W1[k * 128 + n];
        WT2[t] = (_Float16)W2[k * 128 + n];
    }
}

// ---------------- bucketA: bin edges by dst bucket ----------------
__global__ __launch_bounds__(256) void bucketA(const int* __restrict__ ei,
                                               int* __restrict__ tails,
                                               int* __restrict__ bdata) {
    __shared__ int hist[NBUCK];
    __shared__ int lbase[NBUCK];
    int t = threadIdx.x;
    int e0 = blockIdx.x * (256 * EPT);
    for (int i = t; i < NBUCK; i += 256) hist[i] = 0;
    __syncthreads();

    int bb[EPT], pk[EPT], rk[EPT];
#pragma unroll
    for (int i = 0; i < EPT; ++i) {
        int e = e0 + i * 256 + t;
        bb[i] = -1;
        if (e < ETOT) {
            int s, d;
            if (e < N_EDGES) { s = ei[e]; d = ei[N_EDGES + e]; }
            else             { s = d = e - N_EDGES; }
            bb[i] = d >> 8;
            pk[i] = s | ((d & 255) << 16);
            rk[i] = atomicAdd(&hist[bb[i]], 1);
        }
    }
    __syncthreads();
    for (int i = t; i < NBUCK; i += 256)
        lbase[i] = atomicAdd(&tails[i], hist[i]);
    __syncthreads();
#pragma unroll
    for (int i = 0; i < EPT; ++i)
        if (bb[i] >= 0) bdata[bb[i] * BCAP + lbase[bb[i]] + rk[i]] = pk[i];
}

// ---------------- scanBuckets ----------------
__global__ void scanBuckets(const int* __restrict__ tails,
                            int* __restrict__ csrBase,
                            int* __restrict__ rowptr) {
    __shared__ int sh[256];
    int t = threadIdx.x;
    int c = (t < NBUCK) ? tails[t] : 0;
    sh[t] = c;
    __syncthreads();
    for (int off = 1; off < 256; off <<= 1) {
        int add = (t >= off) ? sh[t - off] : 0;
        __syncthreads();
        sh[t] += add;
        __syncthreads();
    }
    if (t < NBUCK) csrBase[t] = sh[t] - c;
    if (t == NBUCK - 1) rowptr[N_NODES] = sh[t];
}

// ---------------- bucketB: per-bucket CSR fill ----------------
__global__ __launch_bounds__(256) void bucketB(const int* __restrict__ bdata,
                                               const int* __restrict__ tails,
                                               const int* __restrict__ csrBase,
                                               int* __restrict__ rowptr,
                                               int* __restrict__ csr) {
    __shared__ int hist[256];
    __shared__ int scanws[256];
    int b = blockIdx.x;
    int t = threadIdx.x;
    int nodes0 = b << 8;
    int nnodes = min(256, N_NODES - nodes0);
    int cnt  = tails[b];
    int base = csrBase[b];
    const int* bd = &bdata[b * BCAP];

    hist[t] = 0;
    __syncthreads();
    for (int j = t; j < cnt; j += 256) atomicAdd(&hist[bd[j] >> 16], 1);
    __syncthreads();
    scanws[t] = hist[t];
    __syncthreads();
    for (int off = 1; off < 256; off <<= 1) {
        int add = (t >= off) ? scanws[t - off] : 0;
        __syncthreads();
        scanws[t] += add;
        __syncthreads();
    }
    int excl = scanws[t] - hist[t];
    if (t < nnodes) rowptr[nodes0 + t] = base + excl;
    __syncthreads();
    hist[t] = excl;
    __syncthreads();
    for (int j = t; j < cnt; j += 256) {
        int pkv = bd[j];
        int pos = atomicAdd(&hist[pkv >> 16], 1);
        csr[base + pos] = pkv & 0xFFFF;
    }
}

// ---------------- MFMA GEMM + fused attention scores ----------------
// H16[M,128] = fp16( Xin[M,128] @ W[128,128] ), scores from fp32 acc.
// WT: W transposed [n][k] fp16. LDS-staged with k ^= (n&7)<<3 swizzle.
// Block = 4 waves x 16 rows. Wave: 8 col-tiles x 4 K-steps of
// mfma_f32_16x16x32_f16. C/D: col=lane&15, row=(lane>>4)*4+reg (m89).
template<bool FP32IN>
__global__ __launch_bounds__(256) void gemmMFMA(const void* __restrict__ Xin,
                                                const _Float16* __restrict__ WT,
                                                const float* __restrict__ att_s,
                                                const float* __restrict__ att_d,
                                                _Float16* __restrict__ H16,
                                                float2* __restrict__ a_src,
                                                float2* __restrict__ a_dst) {
    __shared__ _Float16 wt[128][128];   // 32 KB, swizzled
    int t = threadIdx.x;

    // stage WT -> LDS (coalesced 16B reads, swizzled writes)
    for (int i = t; i < 128 * 16; i += 256) {
        int n = i >> 4, ch = i & 15;
        int k0 = ch * 8;
        half8 v = *(const half8*)&WT[n * 128 + k0];
        *(half8*)&wt[n][k0 ^ ((n & 7) << 3)] = v;
    }

    int w = t >> 6, lane = t & 63;
    int hi = lane >> 4, l16 = lane & 15;
    int rbase = blockIdx.x * 64 + w * 16;
    int arow = min(rbase + l16, N_NODES - 1);

    // A fragments: lane&15 = row, k = kb*32 + hi*8 + j
    half8 a[4];
    if (FP32IN) {
        const float* X = (const float*)Xin;
#pragma unroll
        for (int kb = 0; kb < 4; ++kb) {
            int k0 = kb * 32 + hi * 8;
            float4 x0 = *(const float4*)&X[(size_t)arow * 128 + k0];
            float4 x1 = *(const float4*)&X[(size_t)arow * 128 + k0 + 4];
            half8 v;
            v[0] = (_Float16)x0.x; v[1] = (_Float16)x0.y;
            v[2] = (_Float16)x0.z; v[3] = (_Float16)x0.w;
            v[4] = (_Float16)x1.x; v[5] = (_Float16)x1.y;
            v[6] = (_Float16)x1.z; v[7] = (_Float16)x1.w;
            a[kb] = v;
        }
    } else {
        const _Float16* X = (const _Float16*)Xin;
#pragma unroll
        for (int kb = 0; kb < 4; ++kb)
            a[kb] = *(const half8*)&X[(size_t)arow * 128 + kb * 32 + hi * 8];
    }

    __syncthreads();

    float4v acc[8];
#pragma unroll
    for (int ct = 0; ct < 8; ++ct) {
        float4v c = {0.f, 0.f, 0.f, 0.f};
        int n = ct * 16 + l16;               // B: lane&15 = col
#pragma unroll
        for (int kb = 0; kb < 4; ++kb) {
            int k0 = (kb * 32 + hi * 8) ^ ((n & 7) << 3);
            half8 b = *(const half8*)&wt[n][k0];
            c = __builtin_amdgcn_mfma_f32_16x16x32_f16(a[kb], b, c, 0, 0, 0);
        }
        acc[ct] = c;
    }

    // epilogue: H16 stores (scalar fp16) + fused attention scores
    int grow0 = rbase + hi * 4;
#pragma unroll
    for (int ct = 0; ct < 8; ++ct) {
#pragma unroll
        for (int r = 0; r < 4; ++r) {
            int grow = grow0 + r;
            if (grow < N_NODES)
                H16[(size_t)grow * 128 + ct * 16 + l16] = (_Float16)acc[ct][r];
        }
    }

    float as_[8], ad_[8];
#pragma unroll
    for (int ct = 0; ct < 8; ++ct) {
        as_[ct] = att_s[ct * 16 + l16];
        ad_[ct] = att_d[ct * 16 + l16];
    }
#pragma unroll
    for (int r = 0; r < 4; ++r) {
        float s0 = 0.f, s1 = 0.f, d0 = 0.f, d1 = 0.f;
#pragma unroll
        for (int ct = 0; ct < 4; ++ct) { s0 += acc[ct][r] * as_[ct]; d0 += acc[ct][r] * ad_[ct]; }
#pragma unroll
        for (int ct = 4; ct < 8; ++ct) { s1 += acc[ct][r] * as_[ct]; d1 += acc[ct][r] * ad_[ct]; }
        for (int off = 1; off < 16; off <<= 1) {
            s0 += __shfl_xor(s0, off); s1 += __shfl_xor(s1, off);
            d0 += __shfl_xor(d0, off); d1 += __shfl_xor(d1, off);
        }
        int grow = grow0 + r;
        if (l16 == 0 && grow < N_NODES) {
            a_src[grow] = make_float2(s0, s1);
            a_dst[grow] = make_float2(d0, d1);
        }
    }
}

__device__ __forceinline__ float leaky(float x) { return x > 0.f ? x : NEG * x; }

// ---------------- softmax + aggregation: one wave per dst node ----------------
__global__ __launch_bounds__(256) void aggk(const __half* __restrict__ H16,
                                            const float2* __restrict__ a_src,
                                            const float2* __restrict__ a_dst,
                                            const int* __restrict__ rowptr,
                                            const int* __restrict__ csr,
                                            const float* __restrict__ bias,
                                            float* __restrict__ outp,
                                            _Float16* __restrict__ out16) {
    int wid = (blockIdx.x * 256 + threadIdx.x) >> 6;
    int lane = threadIdx.x & 63;
    if (wid >= N_NODES) return;
    int rbeg = rowptr[wid], rend = rowptr[wid + 1];
    float2 ad = a_dst[wid];

    int grp = lane >> 4;
    int gl  = lane & 15;
    int head = gl >> 3;
    float adh = head ? ad.y : ad.x;
    int f = gl * 8;

    float acc[8] = {0.f, 0.f, 0.f, 0.f, 0.f, 0.f, 0.f, 0.f};
    float denom = 0.f;
#pragma unroll 2
    for (int j = rbeg + grp; j < rend; j += 4) {
        int s = csr[j];
        float2 as = a_src[s];
        float w = __expf(leaky((head ? as.y : as.x) + adh));
        uint4 raw = *(const uint4*)&H16[(size_t)s * 128 + f];
        float2 f0 = __half22float2(*(__half2*)&raw.x);
        float2 f1 = __half22float2(*(__half2*)&raw.y);
        float2 f2 = __half22float2(*(__half2*)&raw.z);
        float2 f3 = __half22float2(*(__half2*)&raw.w);
        acc[0] += w * f0.x; acc[1] += w * f0.y;
        acc[2] += w * f1.x; acc[3] += w * f1.y;
        acc[4] += w * f2.x; acc[5] += w * f2.y;
        acc[6] += w * f3.x; acc[7] += w * f3.y;
        denom += w;
    }
#pragma unroll
    for (int off = 16; off <= 32; off <<= 1) {
#pragma unroll
        for (int i = 0; i < 8; ++i) acc[i] += __shfl_xor(acc[i], off);
        denom += __shfl_xor(denom, off);
    }

    if (grp == 0) {
        float inv = 1.f / (denom + 1e-16f);
        float4 bb0 = *(const float4*)&bias[f];
        float4 bb1 = *(const float4*)&bias[f + 4];
        float o[8];
        o[0] = fmaxf(acc[0] * inv + bb0.x, 0.f);
        o[1] = fmaxf(acc[1] * inv + bb0.y, 0.f);
        o[2] = fmaxf(acc[2] * inv + bb0.z, 0.f);
        o[3] = fmaxf(acc[3] * inv + bb0.w, 0.f);
        o[4] = fmaxf(acc[4] * inv + bb1.x, 0.f);
        o[5] = fmaxf(acc[5] * inv + bb1.y, 0.f);
        o[6] = fmaxf(acc[6] * inv + bb1.z, 0.f);
        o[7] = fmaxf(acc[7] * inv + bb1.w, 0.f);
        *(float4*)&outp[(size_t)wid * 128 + f]     = make_float4(o[0], o[1], o[2], o[3]);
        *(float4*)&outp[(size_t)wid * 128 + f + 4] = make_float4(o[4], o[5], o[6], o[7]);
        half8 h;
#pragma unroll
        for (int i = 0; i < 8; ++i) h[i] = (_Float16)o[i];
        *(half8*)&out16[(size_t)wid * 128 + f] = h;
    }
}

// ---------------- pooling ----------------
__global__ void countk(const int* __restrict__ batch, int* cnt) {
    int g = threadIdx.x;
    if (g >= GRAPHS) return;
    int lo = 0, hi = N_NODES;
    while (lo < hi) { int mid = (lo + hi) >> 1; if (batch[mid] < g) lo = mid + 1; else hi = mid; }
    int lb = lo;
    lo = 0; hi = N_NODES;
    while (lo < hi) { int mid = (lo + hi) >> 1; if (batch[mid] < g + 1) lo = mid + 1; else hi = mid; }
    cnt[g] = lo - lb;
}

__global__ void poolk(const float* __restrict__ H, const int* __restrict__ batch,
                      float* __restrict__ sums) {
    int f = threadIdx.x;            // 128 threads
    int n0 = blockIdx.x * 64;
    if (n0 >= N_NODES) return;
    int n1 = min(n0 + 64, N_NODES);
    int g = batch[n0];
    float run = 0.f;
    for (int n = n0; n < n1; ++n) {
        int gn = batch[n];
        if (gn != g) { atomicAdd(&sums[g * 128 + f], run); run = 0.f; g = gn; }
        run += H[(size_t)n * 128 + f];
    }
    atomicAdd(&sums[g * 128 + f], run);
}

__global__ void finalk(const float* __restrict__ sums, const int* __restrict__ cnt,
                       const float* __restrict__ Wl, const float* __restrict__ bl,
                       float* __restrict__ out) {
    int t = threadIdx.x;
    if (t >= GRAPHS * OUTF) return;
    int g = t / OUTF, o = t % OUTF;
    float inv = 1.f / fmaxf((float)cnt[g], 1.f);
    float acc = 0.f;
#pragma unroll 8
    for (int k = 0; k < 128; ++k) acc += sums[g * 128 + k] * Wl[k * OUTF + o];
    out[t] = acc * inv + bl[o];
}

extern "C" void kernel_launch(void* const* d_in, const int* in_sizes, int n_in,
                              void* d_out, int out_size, void* d_ws, size_t ws_size,
                              hipStream_t stream) {
    const float* x        = (const float*)d_in[0];
    const int*   ei       = (const int*)d_in[1];
    const int*   batch    = (const int*)d_in[2];
    const float* W1       = (const float*)d_in[3];
    const float* att_src1 = (const float*)d_in[4];
    const float* att_dst1 = (const float*)d_in[5];
    const float* b1       = (const float*)d_in[6];
    const float* W2       = (const float*)d_in[7];
    const float* att_src2 = (const float*)d_in[8];
    const float* att_dst2 = (const float*)d_in[9];
    const float* b2       = (const float*)d_in[10];
    const float* Wl       = (const float*)d_in[11];
    const float* bl       = (const float*)d_in[12];
    float* out = (float*)d_out;

    size_t off = 0;
    auto alloc = [&](size_t bytes) -> void* {
        void* p = (char*)d_ws + off;
        off = (off + bytes + 255) & ~(size_t)255;
        return p;
    };
    float*    B       = (float*)alloc((size_t)N_NODES * 128 * 4);
    _Float16* H16     = (_Float16*)alloc((size_t)N_NODES * 128 * 2);
    _Float16* B16     = (_Float16*)alloc((size_t)N_NODES * 128 * 2);
    _Float16* WT1     = (_Float16*)alloc(16384 * 2);
    _Float16* WT2     = (_Float16*)alloc(16384 * 2);
    float2*   a_src   = (float2*)alloc((size_t)N_NODES * 8);
    float2*   a_dst   = (float2*)alloc((size_t)N_NODES * 8);
    int*      bdata   = (int*)alloc((size_t)NBUCK * BCAP * 4);
    int*      tails   = (int*)alloc(NBUCK * 4);
    int*      csrBase = (int*)alloc(NBUCK * 4);
    int*      rowptr  = (int*)alloc((size_t)(N_NODES + 1) * 4);
    int*      csr     = (int*)alloc((size_t)ETOT * 4);
    float*    sums    = (float*)alloc((size_t)GRAPHS * HC * 4);
    int*      cnt     = (int*)alloc(GRAPHS * 4);

    // ---- CSR build + weight conversion ----
    initk<<<32, 256, 0, stream>>>(tails, sums);
    wconv<<<64, 256, 0, stream>>>(W1, W2, WT1, WT2);
    bucketA<<<(ETOT + 2047) / 2048, 256, 0, stream>>>(ei, tails, bdata);
    scanBuckets<<<1, 256, 0, stream>>>(tails, csrBase, rowptr);
    bucketB<<<NBUCK, 256, 0, stream>>>(bdata, tails, csrBase, rowptr, csr);

    const int gemmBlocks = (N_NODES + 63) / 64;             // 782
    const int waveBlocks = (N_NODES * 64 + 255) / 256;      // 12500

    // ---- layer 1 ----
    gemmMFMA<true><<<gemmBlocks, 256, 0, stream>>>(x, WT1, att_src1, att_dst1,
                                                   H16, a_src, a_dst);
    aggk<<<waveBlocks, 256, 0, stream>>>((const __half*)H16, a_src, a_dst,
                                         rowptr, csr, b1, B, B16);

    // ---- layer 2 ----
    gemmMFMA<false><<<gemmBlocks, 256, 0, stream>>>(B16, WT2, att_src2, att_dst2,
                                                    H16, a_src, a_dst);
    aggk<<<waveBlocks, 256, 0, stream>>>((const __half*)H16, a_src, a_dst,
                                         rowptr, csr, b2, B, B16);

    // ---- pool + final linear ----
    countk<<<1, 64, 0, stream>>>(batch, cnt);
    poolk<<<(N_NODES + 63) / 64, 128, 0, stream>>>(B, batch, sums);
    finalk<<<1, 640, 0, stream>>>(sums, cnt, Wl, bl, out);
}

// Round 8
// 173.675 us; speedup vs baseline: 4.5172x; 1.0566x over previous
//
#include <hip/hip_runtime.h>
#include <hip/hip_fp16.h>
#include <math.h>

#define N_NODES 50000
#define N_EDGES 800000
#define ETOT    850000   // N_EDGES + N_NODES self-loops
#define GRAPHS  64
#define FIN     128
#define HC      128      // HEADS*HID
#define OUTF    10
#define NEG     0.2f

#define NBUCK   196      // ceil(50000/256) buckets of 256 dst nodes
#define BCAP    8192     // slots per bucket (mean 4338, sigma ~66 -> safe)
#define EPT     8        // edges per thread in bucketA

using half8   = __attribute__((ext_vector_type(8))) _Float16;
using float4v = __attribute__((ext_vector_type(4))) float;

// ---------------- init: zero bucket tails + pool sums ----------------
__global__ void initk(int* tails, float* sums) {
    int i = blockIdx.x * 256 + threadIdx.x;
    if (i < NBUCK) tails[i] = 0;
    if (i < GRAPHS * HC) sums[i] = 0.f;
}

// ---------------- W -> fp16 transposed copies ----------------
__global__ void wconv(const float* __restrict__ W1, const float* __restrict__ W2,
                      _Float16* __restrict__ WT1, _Float16* __restrict__ WT2) {
    int t = blockIdx.x * 256 + threadIdx.x;
    if (t < 16384) {
        int n = t >> 7, k = t & 127;          // output index WT[n][k]
        WT1[t] = (_Float16)W1[k * 128 + n];
        WT2[t] = (_Float16)W2[k * 128 + n];
    }
}

// ---------------- bucketA: bin edges by dst bucket ----------------
__global__ __launch_bounds__(256) void bucketA(const int* __restrict__ ei,
                                               int* __restrict__ tails,
                                               int* __restrict__ bdata) {
    __shared__ int hist[NBUCK];
    __shared__ int lbase[NBUCK];
    int t = threadIdx.x;
    int e0 = blockIdx.x * (256 * EPT);
    for (int i = t; i < NBUCK; i += 256) hist[i] = 0;
    __syncthreads();

    int bb[EPT], pk[EPT], rk[EPT];
#pragma unroll
    for (int i = 0; i < EPT; ++i) {
        int e = e0 + i * 256 + t;
        bb[i] = -1;
        if (e < ETOT) {
            int s, d;
            if (e < N_EDGES) { s = ei[e]; d = ei[N_EDGES + e]; }
            else             { s = d = e - N_EDGES; }
            bb[i] = d >> 8;
            pk[i] = s | ((d & 255) << 16);
            rk[i] = atomicAdd(&hist[bb[i]], 1);
        }
    }
    __syncthreads();
    for (int i = t; i < NBUCK; i += 256)
        lbase[i] = atomicAdd(&tails[i], hist[i]);
    __syncthreads();
#pragma unroll
    for (int i = 0; i < EPT; ++i)
        if (bb[i] >= 0) bdata[bb[i] * BCAP + lbase[bb[i]] + rk[i]] = pk[i];
}

// ---------------- scanBuckets ----------------
__global__ void scanBuckets(const int* __restrict__ tails,
                            int* __restrict__ csrBase,
                            int* __restrict__ rowptr) {
    __shared__ int sh[256];
    int t = threadIdx.x;
    int c = (t < NBUCK) ? tails[t] : 0;
    sh[t] = c;
    __syncthreads();
    for (int off = 1; off < 256; off <<= 1) {
        int add = (t >= off) ? sh[t - off] : 0;
        __syncthreads();
        sh[t] += add;
        __syncthreads();
    }
    if (t < NBUCK) csrBase[t] = sh[t] - c;
    if (t == NBUCK - 1) rowptr[N_NODES] = sh[t];
}

// ---------------- bucketB: per-bucket CSR fill ----------------
__global__ __launch_bounds__(256) void bucketB(const int* __restrict__ bdata,
                                               const int* __restrict__ tails,
                                               const int* __restrict__ csrBase,
                                               int* __restrict__ rowptr,
                                               int* __restrict__ csr) {
    __shared__ int hist[256];
    __shared__ int scanws[256];
    int b = blockIdx.x;
    int t = threadIdx.x;
    int nodes0 = b << 8;
    int nnodes = min(256, N_NODES - nodes0);
    int cnt  = tails[b];
    int base = csrBase[b];
    const int* bd = &bdata[b * BCAP];

    hist[t] = 0;
    __syncthreads();
    for (int j = t; j < cnt; j += 256) atomicAdd(&hist[bd[j] >> 16], 1);
    __syncthreads();
    scanws[t] = hist[t];
    __syncthreads();
    for (int off = 1; off < 256; off <<= 1) {
        int add = (t >= off) ? scanws[t - off] : 0;
        __syncthreads();
        scanws[t] += add;
        __syncthreads();
    }
    int excl = scanws[t] - hist[t];
    if (t < nnodes) rowptr[nodes0 + t] = base + excl;
    __syncthreads();
    hist[t] = excl;
    __syncthreads();
    for (int j = t; j < cnt; j += 256) {
        int pkv = bd[j];
        int pos = atomicAdd(&hist[pkv >> 16], 1);
        csr[base + pos] = pkv & 0xFFFF;
    }
}

// ---------------- MFMA GEMM + fused attention scores ----------------
template<bool FP32IN>
__global__ __launch_bounds__(256) void gemmMFMA(const void* __restrict__ Xin,
                                                const _Float16* __restrict__ WT,
                                                const float* __restrict__ att_s,
                                                const float* __restrict__ att_d,
                                                _Float16* __restrict__ H16,
                                                float2* __restrict__ a_src,
                                                float2* __restrict__ a_dst) {
    __shared__ _Float16 wt[128][128];   // 32 KB, swizzled
    int t = threadIdx.x;

    for (int i = t; i < 128 * 16; i += 256) {
        int n = i >> 4, ch = i & 15;
        int k0 = ch * 8;
        half8 v = *(const half8*)&WT[n * 128 + k0];
        *(half8*)&wt[n][k0 ^ ((n & 7) << 3)] = v;
    }

    int w = t >> 6, lane = t & 63;
    int hi = lane >> 4, l16 = lane & 15;
    int rbase = blockIdx.x * 64 + w * 16;
    int arow = min(rbase + l16, N_NODES - 1);

    half8 a[4];
    if (FP32IN) {
        const float* X = (const float*)Xin;
#pragma unroll
        for (int kb = 0; kb < 4; ++kb) {
            int k0 = kb * 32 + hi * 8;
            float4 x0 = *(const float4*)&X[(size_t)arow * 128 + k0];
            float4 x1 = *(const float4*)&X[(size_t)arow * 128 + k0 + 4];
            half8 v;
            v[0] = (_Float16)x0.x; v[1] = (_Float16)x0.y;
            v[2] = (_Float16)x0.z; v[3] = (_Float16)x0.w;
            v[4] = (_Float16)x1.x; v[5] = (_Float16)x1.y;
            v[6] = (_Float16)x1.z; v[7] = (_Float16)x1.w;
            a[kb] = v;
        }
    } else {
        const _Float16* X = (const _Float16*)Xin;
#pragma unroll
        for (int kb = 0; kb < 4; ++kb)
            a[kb] = *(const half8*)&X[(size_t)arow * 128 + kb * 32 + hi * 8];
    }

    __syncthreads();

    float4v acc[8];
#pragma unroll
    for (int ct = 0; ct < 8; ++ct) {
        float4v c = {0.f, 0.f, 0.f, 0.f};
        int n = ct * 16 + l16;               // B: lane&15 = col
#pragma unroll
        for (int kb = 0; kb < 4; ++kb) {
            int k0 = (kb * 32 + hi * 8) ^ ((n & 7) << 3);
            half8 b = *(const half8*)&wt[n][k0];
            c = __builtin_amdgcn_mfma_f32_16x16x32_f16(a[kb], b, c, 0, 0, 0);
        }
        acc[ct] = c;
    }

    int grow0 = rbase + hi * 4;
#pragma unroll
    for (int ct = 0; ct < 8; ++ct) {
#pragma unroll
        for (int r = 0; r < 4; ++r) {
            int grow = grow0 + r;
            if (grow < N_NODES)
                H16[(size_t)grow * 128 + ct * 16 + l16] = (_Float16)acc[ct][r];
        }
    }

    float as_[8], ad_[8];
#pragma unroll
    for (int ct = 0; ct < 8; ++ct) {
        as_[ct] = att_s[ct * 16 + l16];
        ad_[ct] = att_d[ct * 16 + l16];
    }
#pragma unroll
    for (int r = 0; r < 4; ++r) {
        float s0 = 0.f, s1 = 0.f, d0 = 0.f, d1 = 0.f;
#pragma unroll
        for (int ct = 0; ct < 4; ++ct) { s0 += acc[ct][r] * as_[ct]; d0 += acc[ct][r] * ad_[ct]; }
#pragma unroll
        for (int ct = 4; ct < 8; ++ct) { s1 += acc[ct][r] * as_[ct]; d1 += acc[ct][r] * ad_[ct]; }
        for (int off = 1; off < 16; off <<= 1) {
            s0 += __shfl_xor(s0, off); s1 += __shfl_xor(s1, off);
            d0 += __shfl_xor(d0, off); d1 += __shfl_xor(d1, off);
        }
        int grow = grow0 + r;
        if (l16 == 0 && grow < N_NODES) {
            a_src[grow] = make_float2(s0, s1);
            a_dst[grow] = make_float2(d0, d1);
        }
    }
}

__device__ __forceinline__ float leaky(float x) { return x > 0.f ? x : NEG * x; }

// ---------------- softmax + aggregation: one wave per dst node ----------------
// 8 groups of 8 lanes: group g walks every 8th edge (8 gather chains/wave),
// lane owns 16 features (2x16B loads). csr prefetch breaks idx->gather dep.
// fp16 output only (consumed by gemm2 / poolk).
__global__ __launch_bounds__(256) void aggk(const __half* __restrict__ H16,
                                            const float2* __restrict__ a_src,
                                            const float2* __restrict__ a_dst,
                                            const int* __restrict__ rowptr,
                                            const int* __restrict__ csr,
                                            const float* __restrict__ bias,
                                            _Float16* __restrict__ out16) {
    int wid = (blockIdx.x * 256 + threadIdx.x) >> 6;
    int lane = threadIdx.x & 63;
    if (wid >= N_NODES) return;
    int rbeg = rowptr[wid], rend = rowptr[wid + 1];
    float2 ad = a_dst[wid];

    int grp = lane >> 3;        // 0..7
    int gl  = lane & 7;         // lane within group
    int head = gl >> 2;         // gl<4 -> head0 (f<64)
    float adh = head ? ad.y : ad.x;
    int f = gl * 16;

    float acc[16];
#pragma unroll
    for (int i = 0; i < 16; ++i) acc[i] = 0.f;
    float denom = 0.f;

    int j = rbeg + grp;
    int sNext = (j < rend) ? csr[j] : 0;
    for (; j < rend; j += 8) {
        int s = sNext;
        int jn = j + 8;
        if (jn < rend) sNext = csr[jn];
        float2 as = a_src[s];
        float wgt = __expf(leaky((head ? as.y : as.x) + adh));
        const uint4* hp = (const uint4*)&H16[(size_t)s * 128 + f];
        uint4 r0 = hp[0];
        uint4 r1 = hp[1];
        float2 p;
        p = __half22float2(*(__half2*)&r0.x); acc[0] += wgt * p.x; acc[1] += wgt * p.y;
        p = __half22float2(*(__half2*)&r0.y); acc[2] += wgt * p.x; acc[3] += wgt * p.y;
        p = __half22float2(*(__half2*)&r0.z); acc[4] += wgt * p.x; acc[5] += wgt * p.y;
        p = __half22float2(*(__half2*)&r0.w); acc[6] += wgt * p.x; acc[7] += wgt * p.y;
        p = __half22float2(*(__half2*)&r1.x); acc[8] += wgt * p.x; acc[9] += wgt * p.y;
        p = __half22float2(*(__half2*)&r1.y); acc[10] += wgt * p.x; acc[11] += wgt * p.y;
        p = __half22float2(*(__half2*)&r1.z); acc[12] += wgt * p.x; acc[13] += wgt * p.y;
        p = __half22float2(*(__half2*)&r1.w); acc[14] += wgt * p.x; acc[15] += wgt * p.y;
        denom += wgt;
    }
    // reduce across the 8 groups (lane bits 3..5)
#pragma unroll
    for (int off = 8; off <= 32; off <<= 1) {
#pragma unroll
        for (int i = 0; i < 16; ++i) acc[i] += __shfl_xor(acc[i], off);
        denom += __shfl_xor(denom, off);
    }

    if (grp == 0) {
        float inv = 1.f / (denom + 1e-16f);
        half8 h0, h1;
#pragma unroll
        for (int i = 0; i < 8; ++i) {
            float o = fmaxf(acc[i] * inv + bias[f + i], 0.f);
            h0[i] = (_Float16)o;
        }
#pragma unroll
        for (int i = 0; i < 8; ++i) {
            float o = fmaxf(acc[8 + i] * inv + bias[f + 8 + i], 0.f);
            h1[i] = (_Float16)o;
        }
        *(half8*)&out16[(size_t)wid * 128 + f]     = h0;
        *(half8*)&out16[(size_t)wid * 128 + f + 8] = h1;
    }
}

// ---------------- pooling ----------------
__global__ void countk(const int* __restrict__ batch, int* cnt) {
    int g = threadIdx.x;
    if (g >= GRAPHS) return;
    int lo = 0, hi = N_NODES;
    while (lo < hi) { int mid = (lo + hi) >> 1; if (batch[mid] < g) lo = mid + 1; else hi = mid; }
    int lb = lo;
    lo = 0; hi = N_NODES;
    while (lo < hi) { int mid = (lo + hi) >> 1; if (batch[mid] < g + 1) lo = mid + 1; else hi = mid; }
    cnt[g] = lo - lb;
}

__global__ void poolk(const _Float16* __restrict__ H, const int* __restrict__ batch,
                      float* __restrict__ sums) {
    int f = threadIdx.x;            // 128 threads
    int n0 = blockIdx.x * 64;
    if (n0 >= N_NODES) return;
    int n1 = min(n0 + 64, N_NODES);
    int g = batch[n0];
    float run = 0.f;
    for (int n = n0; n < n1; ++n) {
        int gn = batch[n];
        if (gn != g) { atomicAdd(&sums[g * 128 + f], run); run = 0.f; g = gn; }
        run += (float)H[(size_t)n * 128 + f];
    }
    atomicAdd(&sums[g * 128 + f], run);
}

__global__ void finalk(const float* __restrict__ sums, const int* __restrict__ cnt,
                       const float* __restrict__ Wl, const float* __restrict__ bl,
                       float* __restrict__ out) {
    int t = threadIdx.x;
    if (t >= GRAPHS * OUTF) return;
    int g = t / OUTF, o = t % OUTF;
    float inv = 1.f / fmaxf((float)cnt[g], 1.f);
    float acc = 0.f;
#pragma unroll 8
    for (int k = 0; k < 128; ++k) acc += sums[g * 128 + k] * Wl[k * OUTF + o];
    out[t] = acc * inv + bl[o];
}

extern "C" void kernel_launch(void* const* d_in, const int* in_sizes, int n_in,
                              void* d_out, int out_size, void* d_ws, size_t ws_size,
                              hipStream_t stream) {
    const float* x        = (const float*)d_in[0];
    const int*   ei       = (const int*)d_in[1];
    const int*   batch    = (const int*)d_in[2];
    const float* W1       = (const float*)d_in[3];
    const float* att_src1 = (const float*)d_in[4];
    const float* att_dst1 = (const float*)d_in[5];
    const float* b1       = (const float*)d_in[6];
    const float* W2       = (const float*)d_in[7];
    const float* att_src2 = (const float*)d_in[8];
    const float* att_dst2 = (const float*)d_in[9];
    const float* b2       = (const float*)d_in[10];
    const float* Wl       = (const float*)d_in[11];
    const float* bl       = (const float*)d_in[12];
    float* out = (float*)d_out;

    size_t off = 0;
    auto alloc = [&](size_t bytes) -> void* {
        void* p = (char*)d_ws + off;
        off = (off + bytes + 255) & ~(size_t)255;
        return p;
    };
    _Float16* H16     = (_Float16*)alloc((size_t)N_NODES * 128 * 2);
    _Float16* B16     = (_Float16*)alloc((size_t)N_NODES * 128 * 2);
    _Float16* WT1     = (_Float16*)alloc(16384 * 2);
    _Float16* WT2     = (_Float16*)alloc(16384 * 2);
    float2*   a_src   = (float2*)alloc((size_t)N_NODES * 8);
    float2*   a_dst   = (float2*)alloc((size_t)N_NODES * 8);
    int*      bdata   = (int*)alloc((size_t)NBUCK * BCAP * 4);
    int*      tails   = (int*)alloc(NBUCK * 4);
    int*      csrBase = (int*)alloc(NBUCK * 4);
    int*      rowptr  = (int*)alloc((size_t)(N_NODES + 1) * 4);
    int*      csr     = (int*)alloc((size_t)ETOT * 4);
    float*    sums    = (float*)alloc((size_t)GRAPHS * HC * 4);
    int*      cnt     = (int*)alloc(GRAPHS * 4);

    // ---- CSR build + weight conversion ----
    initk<<<32, 256, 0, stream>>>(tails, sums);
    wconv<<<64, 256, 0, stream>>>(W1, W2, WT1, WT2);
    bucketA<<<(ETOT + 2047) / 2048, 256, 0, stream>>>(ei, tails, bdata);
    scanBuckets<<<1, 256, 0, stream>>>(tails, csrBase, rowptr);
    bucketB<<<NBUCK, 256, 0, stream>>>(bdata, tails, csrBase, rowptr, csr);

    const int gemmBlocks = (N_NODES + 63) / 64;             // 782
    const int waveBlocks = (N_NODES * 64 + 255) / 256;      // 12500

    // ---- layer 1 ----
    gemmMFMA<true><<<gemmBlocks, 256, 0, stream>>>(x, WT1, att_src1, att_dst1,
                                                   H16, a_src, a_dst);
    aggk<<<waveBlocks, 256, 0, stream>>>((const __half*)H16, a_src, a_dst,
                                         rowptr, csr, b1, B16);

    // ---- layer 2 ----
    gemmMFMA<false><<<gemmBlocks, 256, 0, stream>>>(B16, WT2, att_src2, att_dst2,
                                                    H16, a_src, a_dst);
    aggk<<<waveBlocks, 256, 0, stream>>>((const __half*)H16, a_src, a_dst,
                                         rowptr, csr, b2, B16);

    // ---- pool + final linear ----
    countk<<<1, 64, 0, stream>>>(batch, cnt);
    poolk<<<(N_NODES + 63) / 64, 128, 0, stream>>>(B16, batch, sums);
    finalk<<<1, 640, 0, stream>>>(sums, cnt, Wl, bl, out);
}

// Round 9
// 168.413 us; speedup vs baseline: 4.6583x; 1.0312x over previous
//
#include <hip/hip_runtime.h>
#include <hip/hip_fp16.h>
#include <math.h>

#define N_NODES 50000
#define N_EDGES 800000
#define ETOT    850000   // N_EDGES + N_NODES self-loops
#define GRAPHS  64
#define FIN     128
#define HC      128      // HEADS*HID
#define OUTF    10
#define NEG     0.2f

#define NBUCK   196      // ceil(50000/256) buckets of 256 dst nodes
#define BCAP    8192     // slots per bucket (mean 4338, sigma ~66 -> safe)
#define EPT     8        // edges per thread in bucketA
#define GEMMB   782      // (N_NODES+63)/64
#define ABLK    416      // (ETOT+2047)/2048

using half8   = __attribute__((ext_vector_type(8))) _Float16;
using float4v = __attribute__((ext_vector_type(4))) float;

// ---------------- setup: W->fp16 transposed, zero tails + pool sums ----------------
__global__ void setupk(const float* __restrict__ W1, const float* __restrict__ W2,
                       _Float16* __restrict__ WT1, _Float16* __restrict__ WT2,
                       int* __restrict__ tails, float* __restrict__ sums) {
    int i = blockIdx.x * 256 + threadIdx.x;
    if (i < 16384) {
        int n = i >> 7, k = i & 127;          // output index WT[n][k]
        WT1[i] = (_Float16)W1[k * 128 + n];
        WT2[i] = (_Float16)W2[k * 128 + n];
    }
    if (i < NBUCK) tails[i] = 0;
    if (i < GRAPHS * HC) sums[i] = 0.f;
}

// ---------------- GEMM body (device): MFMA + fused attention scores ----------------
// H16[M,128] = fp16( Xin[M,128] @ W[128,128] ), scores from fp32 acc.
// WT staged in LDS with k ^= (n&7)<<3 swizzle. Wave: 8 col-tiles x 4 K-steps
// of mfma_f32_16x16x32_f16. C/D: col=lane&15, row=(lane>>4)*4+reg (m89).
template<bool FP32IN>
__device__ __forceinline__ void gemm_body(int bid, int t, _Float16 (*wt)[128],
                                          const void* __restrict__ Xin,
                                          const _Float16* __restrict__ WT,
                                          const float* __restrict__ att_s,
                                          const float* __restrict__ att_d,
                                          _Float16* __restrict__ H16,
                                          float2* __restrict__ a_src,
                                          float2* __restrict__ a_dst) {
    for (int i = t; i < 128 * 16; i += 256) {
        int n = i >> 4, ch = i & 15;
        int k0 = ch * 8;
        half8 v = *(const half8*)&WT[n * 128 + k0];
        *(half8*)&wt[n][k0 ^ ((n & 7) << 3)] = v;
    }

    int w = t >> 6, lane = t & 63;
    int hi = lane >> 4, l16 = lane & 15;
    int rbase = bid * 64 + w * 16;
    int arow = min(rbase + l16, N_NODES - 1);

    half8 a[4];
    if (FP32IN) {
        const float* X = (const float*)Xin;
#pragma unroll
        for (int kb = 0; kb < 4; ++kb) {
            int k0 = kb * 32 + hi * 8;
            float4 x0 = *(const float4*)&X[(size_t)arow * 128 + k0];
            float4 x1 = *(const float4*)&X[(size_t)arow * 128 + k0 + 4];
            half8 v;
            v[0] = (_Float16)x0.x; v[1] = (_Float16)x0.y;
            v[2] = (_Float16)x0.z; v[3] = (_Float16)x0.w;
            v[4] = (_Float16)x1.x; v[5] = (_Float16)x1.y;
            v[6] = (_Float16)x1.z; v[7] = (_Float16)x1.w;
            a[kb] = v;
        }
    } else {
        const _Float16* X = (const _Float16*)Xin;
#pragma unroll
        for (int kb = 0; kb < 4; ++kb)
            a[kb] = *(const half8*)&X[(size_t)arow * 128 + kb * 32 + hi * 8];
    }

    __syncthreads();

    float4v acc[8];
#pragma unroll
    for (int ct = 0; ct < 8; ++ct) {
        float4v c = {0.f, 0.f, 0.f, 0.f};
        int n = ct * 16 + l16;               // B: lane&15 = col
#pragma unroll
        for (int kb = 0; kb < 4; ++kb) {
            int k0 = (kb * 32 + hi * 8) ^ ((n & 7) << 3);
            half8 b = *(const half8*)&wt[n][k0];
            c = __builtin_amdgcn_mfma_f32_16x16x32_f16(a[kb], b, c, 0, 0, 0);
        }
        acc[ct] = c;
    }

    int grow0 = rbase + hi * 4;
#pragma unroll
    for (int ct = 0; ct < 8; ++ct) {
#pragma unroll
        for (int r = 0; r < 4; ++r) {
            int grow = grow0 + r;
            if (grow < N_NODES)
                H16[(size_t)grow * 128 + ct * 16 + l16] = (_Float16)acc[ct][r];
        }
    }

    float as_[8], ad_[8];
#pragma unroll
    for (int ct = 0; ct < 8; ++ct) {
        as_[ct] = att_s[ct * 16 + l16];
        ad_[ct] = att_d[ct * 16 + l16];
    }
#pragma unroll
    for (int r = 0; r < 4; ++r) {
        float s0 = 0.f, s1 = 0.f, d0 = 0.f, d1 = 0.f;
#pragma unroll
        for (int ct = 0; ct < 4; ++ct) { s0 += acc[ct][r] * as_[ct]; d0 += acc[ct][r] * ad_[ct]; }
#pragma unroll
        for (int ct = 4; ct < 8; ++ct) { s1 += acc[ct][r] * as_[ct]; d1 += acc[ct][r] * ad_[ct]; }
        for (int off = 1; off < 16; off <<= 1) {
            s0 += __shfl_xor(s0, off); s1 += __shfl_xor(s1, off);
            d0 += __shfl_xor(d0, off); d1 += __shfl_xor(d1, off);
        }
        int grow = grow0 + r;
        if (l16 == 0 && grow < N_NODES) {
            a_src[grow] = make_float2(s0, s1);
            a_dst[grow] = make_float2(d0, d1);
        }
    }
}

// ---------------- bucketA body (device): bin edges by dst bucket ----------------
__device__ __forceinline__ void bucketA_body(int bid, int t,
                                             int* hist, int* lbase,
                                             const int* __restrict__ ei,
                                             int* __restrict__ tails,
                                             int* __restrict__ bdata) {
    int e0 = bid * (256 * EPT);
    for (int i = t; i < NBUCK; i += 256) hist[i] = 0;
    __syncthreads();

    int bb[EPT], pk[EPT], rk[EPT];
#pragma unroll
    for (int i = 0; i < EPT; ++i) {
        int e = e0 + i * 256 + t;
        bb[i] = -1;
        if (e < ETOT) {
            int s, d;
            if (e < N_EDGES) { s = ei[e]; d = ei[N_EDGES + e]; }
            else             { s = d = e - N_EDGES; }
            bb[i] = d >> 8;
            pk[i] = s | ((d & 255) << 16);
            rk[i] = atomicAdd(&hist[bb[i]], 1);
        }
    }
    __syncthreads();
    for (int i = t; i < NBUCK; i += 256)
        lbase[i] = atomicAdd(&tails[i], hist[i]);
    __syncthreads();
#pragma unroll
    for (int i = 0; i < EPT; ++i)
        if (bb[i] >= 0) bdata[bb[i] * BCAP + lbase[bb[i]] + rk[i]] = pk[i];
}

// ---------------- fused: gemm layer-1 blocks + bucketA blocks ----------------
__global__ __launch_bounds__(256) void fusedA(const float* __restrict__ x,
                                              const _Float16* __restrict__ WT1,
                                              const float* __restrict__ att_s,
                                              const float* __restrict__ att_d,
                                              _Float16* __restrict__ H16,
                                              float2* __restrict__ a_src,
                                              float2* __restrict__ a_dst,
                                              const int* __restrict__ ei,
                                              int* __restrict__ tails,
                                              int* __restrict__ bdata) {
    __shared__ _Float16 wt[128][128];   // 32 KB (gemm blocks)
    __shared__ int hist[NBUCK];         // bucketA blocks
    __shared__ int lbase[NBUCK];
    int t = threadIdx.x;
    if (blockIdx.x < GEMMB) {
        gemm_body<true>(blockIdx.x, t, wt, x, WT1, att_s, att_d, H16, a_src, a_dst);
    } else {
        bucketA_body(blockIdx.x - GEMMB, t, hist, lbase, ei, tails, bdata);
    }
}

// ---------------- standalone gemm (layer 2) ----------------
__global__ __launch_bounds__(256) void gemmMFMA(const _Float16* __restrict__ Xin,
                                                const _Float16* __restrict__ WT,
                                                const float* __restrict__ att_s,
                                                const float* __restrict__ att_d,
                                                _Float16* __restrict__ H16,
                                                float2* __restrict__ a_src,
                                                float2* __restrict__ a_dst) {
    __shared__ _Float16 wt[128][128];
    gemm_body<false>(blockIdx.x, threadIdx.x, wt, Xin, WT, att_s, att_d, H16, a_src, a_dst);
}

// ---------------- bucketB: per-bucket CSR fill (self-computed base) ----------------
__global__ __launch_bounds__(256) void bucketB(const int* __restrict__ bdata,
                                               const int* __restrict__ tails,
                                               int* __restrict__ rowptr,
                                               int* __restrict__ csr) {
    __shared__ int hist[256];
    __shared__ int scanws[256];
    int b = blockIdx.x;
    int t = threadIdx.x;

    // scan bucket counts -> this bucket's csr base (replaces scanBuckets kernel)
    int cb = (t < NBUCK) ? tails[t] : 0;
    scanws[t] = cb;
    __syncthreads();
    for (int off = 1; off < 256; off <<= 1) {
        int add = (t >= off) ? scanws[t - off] : 0;
        __syncthreads();
        scanws[t] += add;
        __syncthreads();
    }
    int base = scanws[b] - tails[b];       // exclusive prefix at b (uniform read)
    if (b == NBUCK - 1 && t == 0) rowptr[N_NODES] = scanws[NBUCK - 1];
    int cnt = tails[b];
    int nodes0 = b << 8;
    int nnodes = min(256, N_NODES - nodes0);
    const int* bd = &bdata[b * BCAP];
    __syncthreads();

    hist[t] = 0;
    __syncthreads();
    for (int j = t; j < cnt; j += 256) atomicAdd(&hist[bd[j] >> 16], 1);
    __syncthreads();
    scanws[t] = hist[t];
    __syncthreads();
    for (int off = 1; off < 256; off <<= 1) {
        int add = (t >= off) ? scanws[t - off] : 0;
        __syncthreads();
        scanws[t] += add;
        __syncthreads();
    }
    int excl = scanws[t] - hist[t];
    if (t < nnodes) rowptr[nodes0 + t] = base + excl;
    __syncthreads();
    hist[t] = excl;
    __syncthreads();
    for (int j = t; j < cnt; j += 256) {
        int pkv = bd[j];
        int pos = atomicAdd(&hist[pkv >> 16], 1);
        csr[base + pos] = pkv & 0xFFFF;
    }
}

__device__ __forceinline__ float leaky(float x) { return x > 0.f ? x : NEG * x; }

// ---------------- softmax + aggregation: one wave per dst node ----------------
// 8 groups of 8 lanes: group g walks every 8th edge (8 gather chains/wave),
// lane owns 16 features (2x16B loads). csr + a_src prefetched one edge ahead.
__global__ __launch_bounds__(256) void aggk(const __half* __restrict__ H16,
                                            const float2* __restrict__ a_src,
                                            const float2* __restrict__ a_dst,
                                            const int* __restrict__ rowptr,
                                            const int* __restrict__ csr,
                                            const float* __restrict__ bias,
                                            _Float16* __restrict__ out16) {
    int wid = (blockIdx.x * 256 + threadIdx.x) >> 6;
    int lane = threadIdx.x & 63;
    if (wid >= N_NODES) return;
    int rbeg = rowptr[wid], rend = rowptr[wid + 1];
    float2 ad = a_dst[wid];

    int grp = lane >> 3;        // 0..7
    int gl  = lane & 7;         // lane within group
    int head = gl >> 2;         // gl<4 -> head0 (f<64)
    float adh = head ? ad.y : ad.x;
    int f = gl * 16;

    float acc[16];
#pragma unroll
    for (int i = 0; i < 16; ++i) acc[i] = 0.f;
    float denom = 0.f;

    int j = rbeg + grp;
    int sNext = 0;
    float2 asNext = make_float2(0.f, 0.f);
    if (j < rend) { sNext = csr[j]; asNext = a_src[sNext]; }
    for (; j < rend; j += 8) {
        int s = sNext;
        float2 as = asNext;
        int jn = j + 8;
        if (jn < rend) { sNext = csr[jn]; asNext = a_src[sNext]; }
        float wgt = __expf(leaky((head ? as.y : as.x) + adh));
        const uint4* hp = (const uint4*)&H16[(size_t)s * 128 + f];
        uint4 r0 = hp[0];
        uint4 r1 = hp[1];
        float2 p;
        p = __half22float2(*(__half2*)&r0.x); acc[0] += wgt * p.x; acc[1] += wgt * p.y;
        p = __half22float2(*(__half2*)&r0.y); acc[2] += wgt * p.x; acc[3] += wgt * p.y;
        p = __half22float2(*(__half2*)&r0.z); acc[4] += wgt * p.x; acc[5] += wgt * p.y;
        p = __half22float2(*(__half2*)&r0.w); acc[6] += wgt * p.x; acc[7] += wgt * p.y;
        p = __half22float2(*(__half2*)&r1.x); acc[8] += wgt * p.x; acc[9] += wgt * p.y;
        p = __half22float2(*(__half2*)&r1.y); acc[10] += wgt * p.x; acc[11] += wgt * p.y;
        p = __half22float2(*(__half2*)&r1.z); acc[12] += wgt * p.x; acc[13] += wgt * p.y;
        p = __half22float2(*(__half2*)&r1.w); acc[14] += wgt * p.x; acc[15] += wgt * p.y;
        denom += wgt;
    }
    // reduce across the 8 groups (lane bits 3..5)
#pragma unroll
    for (int off = 8; off <= 32; off <<= 1) {
#pragma unroll
        for (int i = 0; i < 16; ++i) acc[i] += __shfl_xor(acc[i], off);
        denom += __shfl_xor(denom, off);
    }

    if (grp == 0) {
        float inv = 1.f / (denom + 1e-16f);
        half8 h0, h1;
#pragma unroll
        for (int i = 0; i < 8; ++i) {
            float o = fmaxf(acc[i] * inv + bias[f + i], 0.f);
            h0[i] = (_Float16)o;
        }
#pragma unroll
        for (int i = 0; i < 8; ++i) {
            float o = fmaxf(acc[8 + i] * inv + bias[f + 8 + i], 0.f);
            h1[i] = (_Float16)o;
        }
        *(half8*)&out16[(size_t)wid * 128 + f]     = h0;
        *(half8*)&out16[(size_t)wid * 128 + f + 8] = h1;
    }
}

// ---------------- pooling ----------------
__global__ void poolk(const _Float16* __restrict__ H, const int* __restrict__ batch,
                      float* __restrict__ sums) {
    int f = threadIdx.x;            // 128 threads
    int n0 = blockIdx.x * 64;
    if (n0 >= N_NODES) return;
    int n1 = min(n0 + 64, N_NODES);
    int g = batch[n0];
    float run = 0.f;
    for (int n = n0; n < n1; ++n) {
        int gn = batch[n];
        if (gn != g) { atomicAdd(&sums[g * 128 + f], run); run = 0.f; g = gn; }
        run += (float)H[(size_t)n * 128 + f];
    }
    atomicAdd(&sums[g * 128 + f], run);
}

// ---------------- final linear (counts via binary search, sorted batch) ----------------
__global__ void finalk(const float* __restrict__ sums, const int* __restrict__ batch,
                       const float* __restrict__ Wl, const float* __restrict__ bl,
                       float* __restrict__ out) {
    int t = threadIdx.x;
    if (t >= GRAPHS * OUTF) return;
    int g = t / OUTF, o = t % OUTF;
    int lo = 0, hi = N_NODES;
    while (lo < hi) { int m = (lo + hi) >> 1; if (batch[m] < g) lo = m + 1; else hi = m; }
    int lb = lo;
    lo = 0; hi = N_NODES;
    while (lo < hi) { int m = (lo + hi) >> 1; if (batch[m] < g + 1) lo = m + 1; else hi = m; }
    float inv = 1.f / fmaxf((float)(lo - lb), 1.f);
    float acc = 0.f;
#pragma unroll 8
    for (int k = 0; k < 128; ++k) acc += sums[g * 128 + k] * Wl[k * OUTF + o];
    out[t] = acc * inv + bl[o];
}

extern "C" void kernel_launch(void* const* d_in, const int* in_sizes, int n_in,
                              void* d_out, int out_size, void* d_ws, size_t ws_size,
                              hipStream_t stream) {
    const float* x        = (const float*)d_in[0];
    const int*   ei       = (const int*)d_in[1];
    const int*   batch    = (const int*)d_in[2];
    const float* W1       = (const float*)d_in[3];
    const float* att_src1 = (const float*)d_in[4];
    const float* att_dst1 = (const float*)d_in[5];
    const float* b1       = (const float*)d_in[6];
    const float* W2       = (const float*)d_in[7];
    const float* att_src2 = (const float*)d_in[8];
    const float* att_dst2 = (const float*)d_in[9];
    const float* b2       = (const float*)d_in[10];
    const float* Wl       = (const float*)d_in[11];
    const float* bl       = (const float*)d_in[12];
    float* out = (float*)d_out;

    size_t off = 0;
    auto alloc = [&](size_t bytes) -> void* {
        void* p = (char*)d_ws + off;
        off = (off + bytes + 255) & ~(size_t)255;
        return p;
    };
    _Float16* H16     = (_Float16*)alloc((size_t)N_NODES * 128 * 2);
    _Float16* B16     = (_Float16*)alloc((size_t)N_NODES * 128 * 2);
    _Float16* WT1     = (_Float16*)alloc(16384 * 2);
    _Float16* WT2     = (_Float16*)alloc(16384 * 2);
    float2*   a_src   = (float2*)alloc((size_t)N_NODES * 8);
    float2*   a_dst   = (float2*)alloc((size_t)N_NODES * 8);
    int*      bdata   = (int*)alloc((size_t)NBUCK * BCAP * 4);
    int*      tails   = (int*)alloc(NBUCK * 4);
    int*      rowptr  = (int*)alloc((size_t)(N_NODES + 1) * 4);
    int*      csr     = (int*)alloc((size_t)ETOT * 4);
    float*    sums    = (float*)alloc((size_t)GRAPHS * HC * 4);

    const int waveBlocks = (N_NODES * 64 + 255) / 256;      // 12500

    // 1. setup (weights fp16-transpose, zero tails/sums)
    setupk<<<64, 256, 0, stream>>>(W1, W2, WT1, WT2, tails, sums);
    // 2. layer-1 GEMM + bucketA in one dispatch (independent work)
    fusedA<<<GEMMB + ABLK, 256, 0, stream>>>(x, WT1, att_src1, att_dst1,
                                             H16, a_src, a_dst, ei, tails, bdata);
    // 3. per-bucket CSR fill (self-computes base from tails)
    bucketB<<<NBUCK, 256, 0, stream>>>(bdata, tails, rowptr, csr);
    // 4. layer-1 aggregation
    aggk<<<waveBlocks, 256, 0, stream>>>((const __half*)H16, a_src, a_dst,
                                         rowptr, csr, b1, B16);
    // 5. layer-2 GEMM
    gemmMFMA<<<GEMMB, 256, 0, stream>>>(B16, WT2, att_src2, att_dst2,
                                        H16, a_src, a_dst);
    // 6. layer-2 aggregation
    aggk<<<waveBlocks, 256, 0, stream>>>((const __half*)H16, a_src, a_dst,
                                         rowptr, csr, b2, B16);
    // 7. pool, 8. final linear (+ per-graph counts)
    poolk<<<(N_NODES + 63) / 64, 128, 0, stream>>>(B16, batch, sums);
    finalk<<<1, 640, 0, stream>>>(sums, batch, Wl, bl, out);
}

// Round 10
// 167.184 us; speedup vs baseline: 4.6926x; 1.0074x over previous
//
#include <hip/hip_runtime.h>
#include <hip/hip_fp16.h>
#include <math.h>

#define N_NODES 50000
#define N_EDGES 800000
#define ETOT    850000   // N_EDGES + N_NODES self-loops
#define GRAPHS  64
#define FIN     128
#define HC      128      // HEADS*HID
#define OUTF    10
#define NEG     0.2f

#define NBUCK   196      // ceil(50000/256) buckets of 256 dst nodes
#define BCAP    8192     // slots per bucket (mean 4338, sigma ~66 -> safe)
#define EPT     8        // edges per thread in bucketA
#define GEMMB   782      // (N_NODES+63)/64
#define ABLK    416      // (ETOT+2047)/2048

using half8   = __attribute__((ext_vector_type(8))) _Float16;
using float4v = __attribute__((ext_vector_type(4))) float;

// ---------------- setup: W->fp16 transposed, zero tails + pool sums ----------------
__global__ void setupk(const float* __restrict__ W1, const float* __restrict__ W2,
                       _Float16* __restrict__ WT1, _Float16* __restrict__ WT2,
                       int* __restrict__ tails, float* __restrict__ sums) {
    int i = blockIdx.x * 256 + threadIdx.x;
    if (i < 16384) {
        int n = i >> 7, k = i & 127;          // output index WT[n][k]
        WT1[i] = (_Float16)W1[k * 128 + n];
        WT2[i] = (_Float16)W2[k * 128 + n];
    }
    if (i < NBUCK) tails[i] = 0;
    if (i < GRAPHS * HC) sums[i] = 0.f;
}

// ---------------- GEMM body (device): MFMA + fused attention scores ----------------
// H16[M,128] = fp16( Xin[M,128] @ W[128,128] ), scores from fp32 acc.
// WT staged in LDS with k ^= (n&7)<<3 swizzle. Wave: 8 col-tiles x 4 K-steps
// of mfma_f32_16x16x32_f16. C/D: col=lane&15, row=(lane>>4)*4+reg (m89).
template<bool FP32IN>
__device__ __forceinline__ void gemm_body(int bid, int t, _Float16 (*wt)[128],
                                          const void* __restrict__ Xin,
                                          const _Float16* __restrict__ WT,
                                          const float* __restrict__ att_s,
                                          const float* __restrict__ att_d,
                                          _Float16* __restrict__ H16,
                                          float2* __restrict__ a_src,
                                          float2* __restrict__ a_dst) {
    for (int i = t; i < 128 * 16; i += 256) {
        int n = i >> 4, ch = i & 15;
        int k0 = ch * 8;
        half8 v = *(const half8*)&WT[n * 128 + k0];
        *(half8*)&wt[n][k0 ^ ((n & 7) << 3)] = v;
    }

    int w = t >> 6, lane = t & 63;
    int hi = lane >> 4, l16 = lane & 15;
    int rbase = bid * 64 + w * 16;
    int arow = min(rbase + l16, N_NODES - 1);

    half8 a[4];
    if (FP32IN) {
        const float* X = (const float*)Xin;
#pragma unroll
        for (int kb = 0; kb < 4; ++kb) {
            int k0 = kb * 32 + hi * 8;
            float4 x0 = *(const float4*)&X[(size_t)arow * 128 + k0];
            float4 x1 = *(const float4*)&X[(size_t)arow * 128 + k0 + 4];
            half8 v;
            v[0] = (_Float16)x0.x; v[1] = (_Float16)x0.y;
            v[2] = (_Float16)x0.z; v[3] = (_Float16)x0.w;
            v[4] = (_Float16)x1.x; v[5] = (_Float16)x1.y;
            v[6] = (_Float16)x1.z; v[7] = (_Float16)x1.w;
            a[kb] = v;
        }
    } else {
        const _Float16* X = (const _Float16*)Xin;
#pragma unroll
        for (int kb = 0; kb < 4; ++kb)
            a[kb] = *(const half8*)&X[(size_t)arow * 128 + kb * 32 + hi * 8];
    }

    __syncthreads();

    float4v acc[8];
#pragma unroll
    for (int ct = 0; ct < 8; ++ct) {
        float4v c = {0.f, 0.f, 0.f, 0.f};
        int n = ct * 16 + l16;               // B: lane&15 = col
#pragma unroll
        for (int kb = 0; kb < 4; ++kb) {
            int k0 = (kb * 32 + hi * 8) ^ ((n & 7) << 3);
            half8 b = *(const half8*)&wt[n][k0];
            c = __builtin_amdgcn_mfma_f32_16x16x32_f16(a[kb], b, c, 0, 0, 0);
        }
        acc[ct] = c;
    }

    int grow0 = rbase + hi * 4;
#pragma unroll
    for (int ct = 0; ct < 8; ++ct) {
#pragma unroll
        for (int r = 0; r < 4; ++r) {
            int grow = grow0 + r;
            if (grow < N_NODES)
                H16[(size_t)grow * 128 + ct * 16 + l16] = (_Float16)acc[ct][r];
        }
    }

    float as_[8], ad_[8];
#pragma unroll
    for (int ct = 0; ct < 8; ++ct) {
        as_[ct] = att_s[ct * 16 + l16];
        ad_[ct] = att_d[ct * 16 + l16];
    }
#pragma unroll
    for (int r = 0; r < 4; ++r) {
        float s0 = 0.f, s1 = 0.f, d0 = 0.f, d1 = 0.f;
#pragma unroll
        for (int ct = 0; ct < 4; ++ct) { s0 += acc[ct][r] * as_[ct]; d0 += acc[ct][r] * ad_[ct]; }
#pragma unroll
        for (int ct = 4; ct < 8; ++ct) { s1 += acc[ct][r] * as_[ct]; d1 += acc[ct][r] * ad_[ct]; }
        for (int off = 1; off < 16; off <<= 1) {
            s0 += __shfl_xor(s0, off); s1 += __shfl_xor(s1, off);
            d0 += __shfl_xor(d0, off); d1 += __shfl_xor(d1, off);
        }
        int grow = grow0 + r;
        if (l16 == 0 && grow < N_NODES) {
            a_src[grow] = make_float2(s0, s1);
            a_dst[grow] = make_float2(d0, d1);
        }
    }
}

// ---------------- bucketA body (device): bin edges by dst bucket ----------------
__device__ __forceinline__ void bucketA_body(int bid, int t,
                                             int* hist, int* lbase,
                                             const int* __restrict__ ei,
                                             int* __restrict__ tails,
                                             int* __restrict__ bdata) {
    int e0 = bid * (256 * EPT);
    for (int i = t; i < NBUCK; i += 256) hist[i] = 0;
    __syncthreads();

    int bb[EPT], pk[EPT], rk[EPT];
#pragma unroll
    for (int i = 0; i < EPT; ++i) {
        int e = e0 + i * 256 + t;
        bb[i] = -1;
        if (e < ETOT) {
            int s, d;
            if (e < N_EDGES) { s = ei[e]; d = ei[N_EDGES + e]; }
            else             { s = d = e - N_EDGES; }
            bb[i] = d >> 8;
            pk[i] = s | ((d & 255) << 16);
            rk[i] = atomicAdd(&hist[bb[i]], 1);
        }
    }
    __syncthreads();
    for (int i = t; i < NBUCK; i += 256)
        lbase[i] = atomicAdd(&tails[i], hist[i]);
    __syncthreads();
#pragma unroll
    for (int i = 0; i < EPT; ++i)
        if (bb[i] >= 0) bdata[bb[i] * BCAP + lbase[bb[i]] + rk[i]] = pk[i];
}

// ---------------- fused: gemm layer-1 blocks + bucketA blocks ----------------
__global__ __launch_bounds__(256) void fusedA(const float* __restrict__ x,
                                              const _Float16* __restrict__ WT1,
                                              const float* __restrict__ att_s,
                                              const float* __restrict__ att_d,
                                              _Float16* __restrict__ H16,
                                              float2* __restrict__ a_src,
                                              float2* __restrict__ a_dst,
                                              const int* __restrict__ ei,
                                              int* __restrict__ tails,
                                              int* __restrict__ bdata) {
    __shared__ _Float16 wt[128][128];   // 32 KB (gemm blocks)
    __shared__ int hist[NBUCK];         // bucketA blocks
    __shared__ int lbase[NBUCK];
    int t = threadIdx.x;
    if (blockIdx.x < GEMMB) {
        gemm_body<true>(blockIdx.x, t, wt, x, WT1, att_s, att_d, H16, a_src, a_dst);
    } else {
        bucketA_body(blockIdx.x - GEMMB, t, hist, lbase, ei, tails, bdata);
    }
}

// ---------------- standalone gemm (layer 2) ----------------
__global__ __launch_bounds__(256) void gemmMFMA(const _Float16* __restrict__ Xin,
                                                const _Float16* __restrict__ WT,
                                                const float* __restrict__ att_s,
                                                const float* __restrict__ att_d,
                                                _Float16* __restrict__ H16,
                                                float2* __restrict__ a_src,
                                                float2* __restrict__ a_dst) {
    __shared__ _Float16 wt[128][128];
    gemm_body<false>(blockIdx.x, threadIdx.x, wt, Xin, WT, att_s, att_d, H16, a_src, a_dst);
}

// ---------------- bucketB: per-bucket CSR fill (self-computed base) ----------------
__global__ __launch_bounds__(256) void bucketB(const int* __restrict__ bdata,
                                               const int* __restrict__ tails,
                                               int* __restrict__ rowptr,
                                               int* __restrict__ csr) {
    __shared__ int hist[256];
    __shared__ int scanws[256];
    int b = blockIdx.x;
    int t = threadIdx.x;

    // scan bucket counts -> this bucket's csr base (replaces scanBuckets kernel)
    int cb = (t < NBUCK) ? tails[t] : 0;
    scanws[t] = cb;
    __syncthreads();
    for (int off = 1; off < 256; off <<= 1) {
        int add = (t >= off) ? scanws[t - off] : 0;
        __syncthreads();
        scanws[t] += add;
        __syncthreads();
    }
    int base = scanws[b] - tails[b];       // exclusive prefix at b (uniform read)
    if (b == NBUCK - 1 && t == 0) rowptr[N_NODES] = scanws[NBUCK - 1];
    int cnt = tails[b];
    int nodes0 = b << 8;
    int nnodes = min(256, N_NODES - nodes0);
    const int* bd = &bdata[b * BCAP];
    __syncthreads();

    hist[t] = 0;
    __syncthreads();
    for (int j = t; j < cnt; j += 256) atomicAdd(&hist[bd[j] >> 16], 1);
    __syncthreads();
    scanws[t] = hist[t];
    __syncthreads();
    for (int off = 1; off < 256; off <<= 1) {
        int add = (t >= off) ? scanws[t - off] : 0;
        __syncthreads();
        scanws[t] += add;
        __syncthreads();
    }
    int excl = scanws[t] - hist[t];
    if (t < nnodes) rowptr[nodes0 + t] = base + excl;
    __syncthreads();
    hist[t] = excl;
    __syncthreads();
    for (int j = t; j < cnt; j += 256) {
        int pkv = bd[j];
        int pos = atomicAdd(&hist[pkv >> 16], 1);
        csr[base + pos] = pkv & 0xFFFF;
    }
}

__device__ __forceinline__ float leaky(float x) { return x > 0.f ? x : NEG * x; }

// ---------------- softmax + aggregation: one wave per dst node ----------------
// 8 groups of 8 lanes: group g walks every 8th edge (8 gather chains/wave),
// lane owns 16 features (2x16B loads). csr + a_src prefetched one edge ahead.
// POOL=false: write fp16 node output. POOL=true: fuse global-mean-pool sums
// (per-wave LDS buffer -> per-graph dedup'd global atomics; no node write).
template<bool POOL>
__global__ __launch_bounds__(256) void aggk(const __half* __restrict__ H16,
                                            const float2* __restrict__ a_src,
                                            const float2* __restrict__ a_dst,
                                            const int* __restrict__ rowptr,
                                            const int* __restrict__ csr,
                                            const float* __restrict__ bias,
                                            _Float16* __restrict__ out16,
                                            const int* __restrict__ batch,
                                            float* __restrict__ sums) {
    __shared__ float pbuf[POOL ? 4 : 1][128];
    __shared__ int pg[4];
    int wid = (blockIdx.x * 256 + threadIdx.x) >> 6;   // grid covers exactly N_NODES
    int t = threadIdx.x;
    int w = t >> 6;
    int lane = t & 63;
    int rbeg = rowptr[wid], rend = rowptr[wid + 1];
    float2 ad = a_dst[wid];

    int grp = lane >> 3;        // 0..7
    int gl  = lane & 7;         // lane within group
    int head = gl >> 2;         // gl<4 -> head0 (f<64)
    float adh = head ? ad.y : ad.x;
    int f = gl * 16;

    float acc[16];
#pragma unroll
    for (int i = 0; i < 16; ++i) acc[i] = 0.f;
    float denom = 0.f;

    int j = rbeg + grp;
    int sNext = 0;
    float2 asNext = make_float2(0.f, 0.f);
    if (j < rend) { sNext = csr[j]; asNext = a_src[sNext]; }
    for (; j < rend; j += 8) {
        int s = sNext;
        float2 as = asNext;
        int jn = j + 8;
        if (jn < rend) { sNext = csr[jn]; asNext = a_src[sNext]; }
        float wgt = __expf(leaky((head ? as.y : as.x) + adh));
        const uint4* hp = (const uint4*)&H16[(size_t)s * 128 + f];
        uint4 r0 = hp[0];
        uint4 r1 = hp[1];
        float2 p;
        p = __half22float2(*(__half2*)&r0.x); acc[0] += wgt * p.x; acc[1] += wgt * p.y;
        p = __half22float2(*(__half2*)&r0.y); acc[2] += wgt * p.x; acc[3] += wgt * p.y;
        p = __half22float2(*(__half2*)&r0.z); acc[4] += wgt * p.x; acc[5] += wgt * p.y;
        p = __half22float2(*(__half2*)&r0.w); acc[6] += wgt * p.x; acc[7] += wgt * p.y;
        p = __half22float2(*(__half2*)&r1.x); acc[8] += wgt * p.x; acc[9] += wgt * p.y;
        p = __half22float2(*(__half2*)&r1.y); acc[10] += wgt * p.x; acc[11] += wgt * p.y;
        p = __half22float2(*(__half2*)&r1.z); acc[12] += wgt * p.x; acc[13] += wgt * p.y;
        p = __half22float2(*(__half2*)&r1.w); acc[14] += wgt * p.x; acc[15] += wgt * p.y;
        denom += wgt;
    }
    // reduce across the 8 groups (lane bits 3..5)
#pragma unroll
    for (int off = 8; off <= 32; off <<= 1) {
#pragma unroll
        for (int i = 0; i < 16; ++i) acc[i] += __shfl_xor(acc[i], off);
        denom += __shfl_xor(denom, off);
    }

    float inv = 1.f / (denom + 1e-16f);
    if (POOL) {
        if (grp == 0) {
            if (gl == 0) pg[w] = batch[wid];
#pragma unroll
            for (int i = 0; i < 16; ++i)
                pbuf[w][f + i] = fmaxf(acc[i] * inv + bias[f + i], 0.f);
        }
        __syncthreads();
        // flush: dedupe the 4 wave-slots by graph id, 1 atomic per feat per graph
        if (t < 128) {
#pragma unroll
            for (int ws = 0; ws < 4; ++ws) {
                bool leader = true;
#pragma unroll
                for (int v = 0; v < ws; ++v) leader = leader && (pg[ws] != pg[v]);
                if (leader) {
                    float s = pbuf[ws][t];
#pragma unroll
                    for (int u = ws + 1; u < 4; ++u)
                        if (pg[u] == pg[ws]) s += pbuf[u][t];
                    atomicAdd(&sums[pg[ws] * 128 + t], s);
                }
            }
        }
    } else {
        if (grp == 0) {
            half8 h0, h1;
#pragma unroll
            for (int i = 0; i < 8; ++i)
                h0[i] = (_Float16)fmaxf(acc[i] * inv + bias[f + i], 0.f);
#pragma unroll
            for (int i = 0; i < 8; ++i)
                h1[i] = (_Float16)fmaxf(acc[8 + i] * inv + bias[f + 8 + i], 0.f);
            *(half8*)&out16[(size_t)wid * 128 + f]     = h0;
            *(half8*)&out16[(size_t)wid * 128 + f + 8] = h1;
        }
    }
}

// ---------------- final linear (counts via binary search, sorted batch) ----------------
__global__ void finalk(const float* __restrict__ sums, const int* __restrict__ batch,
                       const float* __restrict__ Wl, const float* __restrict__ bl,
                       float* __restrict__ out) {
    int t = threadIdx.x;
    if (t >= GRAPHS * OUTF) return;
    int g = t / OUTF, o = t % OUTF;
    int lo = 0, hi = N_NODES;
    while (lo < hi) { int m = (lo + hi) >> 1; if (batch[m] < g) lo = m + 1; else hi = m; }
    int lb = lo;
    lo = 0; hi = N_NODES;
    while (lo < hi) { int m = (lo + hi) >> 1; if (batch[m] < g + 1) lo = m + 1; else hi = m; }
    float inv = 1.f / fmaxf((float)(lo - lb), 1.f);
    float acc = 0.f;
#pragma unroll 8
    for (int k = 0; k < 128; ++k) acc += sums[g * 128 + k] * Wl[k * OUTF + o];
    out[t] = acc * inv + bl[o];
}

extern "C" void kernel_launch(void* const* d_in, const int* in_sizes, int n_in,
                              void* d_out, int out_size, void* d_ws, size_t ws_size,
                              hipStream_t stream) {
    const float* x        = (const float*)d_in[0];
    const int*   ei       = (const int*)d_in[1];
    const int*   batch    = (const int*)d_in[2];
    const float* W1       = (const float*)d_in[3];
    const float* att_src1 = (const float*)d_in[4];
    const float* att_dst1 = (const float*)d_in[5];
    const float* b1       = (const float*)d_in[6];
    const float* W2       = (const float*)d_in[7];
    const float* att_src2 = (const float*)d_in[8];
    const float* att_dst2 = (const float*)d_in[9];
    const float* b2       = (const float*)d_in[10];
    const float* Wl       = (const float*)d_in[11];
    const float* bl       = (const float*)d_in[12];
    float* out = (float*)d_out;

    size_t off = 0;
    auto alloc = [&](size_t bytes) -> void* {
        void* p = (char*)d_ws + off;
        off = (off + bytes + 255) & ~(size_t)255;
        return p;
    };
    _Float16* H16     = (_Float16*)alloc((size_t)N_NODES * 128 * 2);
    _Float16* B16     = (_Float16*)alloc((size_t)N_NODES * 128 * 2);
    _Float16* WT1     = (_Float16*)alloc(16384 * 2);
    _Float16* WT2     = (_Float16*)alloc(16384 * 2);
    float2*   a_src   = (float2*)alloc((size_t)N_NODES * 8);
    float2*   a_dst   = (float2*)alloc((size_t)N_NODES * 8);
    int*      bdata   = (int*)alloc((size_t)NBUCK * BCAP * 4);
    int*      tails   = (int*)alloc(NBUCK * 4);
    int*      rowptr  = (int*)alloc((size_t)(N_NODES + 1) * 4);
    int*      csr     = (int*)alloc((size_t)ETOT * 4);
    float*    sums    = (float*)alloc((size_t)GRAPHS * HC * 4);

    const int waveBlocks = (N_NODES * 64 + 255) / 256;      // 12500 (exact)

    // 1. setup (weights fp16-transpose, zero tails/sums)
    setupk<<<64, 256, 0, stream>>>(W1, W2, WT1, WT2, tails, sums);
    // 2. layer-1 GEMM + bucketA in one dispatch (independent work)
    fusedA<<<GEMMB + ABLK, 256, 0, stream>>>(x, WT1, att_src1, att_dst1,
                                             H16, a_src, a_dst, ei, tails, bdata);
    // 3. per-bucket CSR fill (self-computes base from tails)
    bucketB<<<NBUCK, 256, 0, stream>>>(bdata, tails, rowptr, csr);
    // 4. layer-1 aggregation (writes fp16 node features)
    aggk<false><<<waveBlocks, 256, 0, stream>>>((const __half*)H16, a_src, a_dst,
                                                rowptr, csr, b1, B16, batch, sums);
    // 5. layer-2 GEMM
    gemmMFMA<<<GEMMB, 256, 0, stream>>>(B16, WT2, att_src2, att_dst2,
                                        H16, a_src, a_dst);
    // 6. layer-2 aggregation + fused global-mean-pool sums
    aggk<true><<<waveBlocks, 256, 0, stream>>>((const __half*)H16, a_src, a_dst,
                                               rowptr, csr, b2, nullptr, batch, sums);
    // 7. final linear (+ per-graph counts via binary search)
    finalk<<<1, 640, 0, stream>>>(sums, batch, Wl, bl, out);
}

// Round 11
// 161.098 us; speedup vs baseline: 4.8698x; 1.0378x over previous
//
#include <hip/hip_runtime.h>
#include <hip/hip_fp16.h>
#include <math.h>

#define N_NODES 50000
#define N_EDGES 800000
#define ETOT    850000   // N_EDGES + N_NODES self-loops
#define GRAPHS  64
#define FIN     128
#define HC      128      // HEADS*HID
#define OUTF    10
#define NEG     0.2f

#define NBUCK   196      // ceil(50000/256) buckets of 256 dst nodes
#define BCAP    8192     // slots per bucket (mean 4338, sigma ~66 -> safe)
#define EPT     8        // edges per thread in bucketA
#define GEMMB   782      // (N_NODES+63)/64
#define ABLK    416      // (ETOT+2047)/2048

using half8   = __attribute__((ext_vector_type(8))) _Float16;
using float4v = __attribute__((ext_vector_type(4))) float;

// ---------------- setup: W->fp16 transposed, zero tails + pool sums ----------------
__global__ void setupk(const float* __restrict__ W1, const float* __restrict__ W2,
                       _Float16* __restrict__ WT1, _Float16* __restrict__ WT2,
                       int* __restrict__ tails, float* __restrict__ sums) {
    int i = blockIdx.x * 256 + threadIdx.x;
    if (i < 16384) {
        int n = i >> 7, k = i & 127;          // output index WT[n][k]
        WT1[i] = (_Float16)W1[k * 128 + n];
        WT2[i] = (_Float16)W2[k * 128 + n];
    }
    if (i < NBUCK) tails[i] = 0;
    if (i < GRAPHS * HC) sums[i] = 0.f;
}

// ---------------- GEMM body (device): MFMA + fused attention scores ----------------
// H16[M,128] = fp16( Xin[M,128] @ W[128,128] ), scores from fp32 acc.
// WT staged in LDS with k ^= (n&7)<<3 swizzle. Wave: 8 col-tiles x 4 K-steps
// of mfma_f32_16x16x32_f16. C/D: col=lane&15, row=(lane>>4)*4+reg (m89).
template<bool FP32IN>
__device__ __forceinline__ void gemm_body(int bid, int t, _Float16 (*wt)[128],
                                          const void* __restrict__ Xin,
                                          const _Float16* __restrict__ WT,
                                          const float* __restrict__ att_s,
                                          const float* __restrict__ att_d,
                                          _Float16* __restrict__ H16,
                                          float2* __restrict__ a_src,
                                          float2* __restrict__ a_dst) {
    for (int i = t; i < 128 * 16; i += 256) {
        int n = i >> 4, ch = i & 15;
        int k0 = ch * 8;
        half8 v = *(const half8*)&WT[n * 128 + k0];
        *(half8*)&wt[n][k0 ^ ((n & 7) << 3)] = v;
    }

    int w = t >> 6, lane = t & 63;
    int hi = lane >> 4, l16 = lane & 15;
    int rbase = bid * 64 + w * 16;
    int arow = min(rbase + l16, N_NODES - 1);

    half8 a[4];
    if (FP32IN) {
        const float* X = (const float*)Xin;
#pragma unroll
        for (int kb = 0; kb < 4; ++kb) {
            int k0 = kb * 32 + hi * 8;
            float4 x0 = *(const float4*)&X[(size_t)arow * 128 + k0];
            float4 x1 = *(const float4*)&X[(size_t)arow * 128 + k0 + 4];
            half8 v;
            v[0] = (_Float16)x0.x; v[1] = (_Float16)x0.y;
            v[2] = (_Float16)x0.z; v[3] = (_Float16)x0.w;
            v[4] = (_Float16)x1.x; v[5] = (_Float16)x1.y;
            v[6] = (_Float16)x1.z; v[7] = (_Float16)x1.w;
            a[kb] = v;
        }
    } else {
        const _Float16* X = (const _Float16*)Xin;
#pragma unroll
        for (int kb = 0; kb < 4; ++kb)
            a[kb] = *(const half8*)&X[(size_t)arow * 128 + kb * 32 + hi * 8];
    }

    __syncthreads();

    float4v acc[8];
#pragma unroll
    for (int ct = 0; ct < 8; ++ct) {
        float4v c = {0.f, 0.f, 0.f, 0.f};
        int n = ct * 16 + l16;               // B: lane&15 = col
#pragma unroll
        for (int kb = 0; kb < 4; ++kb) {
            int k0 = (kb * 32 + hi * 8) ^ ((n & 7) << 3);
            half8 b = *(const half8*)&wt[n][k0];
            c = __builtin_amdgcn_mfma_f32_16x16x32_f16(a[kb], b, c, 0, 0, 0);
        }
        acc[ct] = c;
    }

    int grow0 = rbase + hi * 4;
#pragma unroll
    for (int ct = 0; ct < 8; ++ct) {
#pragma unroll
        for (int r = 0; r < 4; ++r) {
            int grow = grow0 + r;
            if (grow < N_NODES)
                H16[(size_t)grow * 128 + ct * 16 + l16] = (_Float16)acc[ct][r];
        }
    }

    float as_[8], ad_[8];
#pragma unroll
    for (int ct = 0; ct < 8; ++ct) {
        as_[ct] = att_s[ct * 16 + l16];
        ad_[ct] = att_d[ct * 16 + l16];
    }
#pragma unroll
    for (int r = 0; r < 4; ++r) {
        float s0 = 0.f, s1 = 0.f, d0 = 0.f, d1 = 0.f;
#pragma unroll
        for (int ct = 0; ct < 4; ++ct) { s0 += acc[ct][r] * as_[ct]; d0 += acc[ct][r] * ad_[ct]; }
#pragma unroll
        for (int ct = 4; ct < 8; ++ct) { s1 += acc[ct][r] * as_[ct]; d1 += acc[ct][r] * ad_[ct]; }
        for (int off = 1; off < 16; off <<= 1) {
            s0 += __shfl_xor(s0, off); s1 += __shfl_xor(s1, off);
            d0 += __shfl_xor(d0, off); d1 += __shfl_xor(d1, off);
        }
        int grow = grow0 + r;
        if (l16 == 0 && grow < N_NODES) {
            a_src[grow] = make_float2(s0, s1);
            a_dst[grow] = make_float2(d0, d1);
        }
    }
}

// ---------------- bucketA body (device): bin edges by dst bucket ----------------
__device__ __forceinline__ void bucketA_body(int bid, int t,
                                             int* hist, int* lbase,
                                             const int* __restrict__ ei,
                                             int* __restrict__ tails,
                                             int* __restrict__ bdata) {
    int e0 = bid * (256 * EPT);
    for (int i = t; i < NBUCK; i += 256) hist[i] = 0;
    __syncthreads();

    int bb[EPT], pk[EPT], rk[EPT];
#pragma unroll
    for (int i = 0; i < EPT; ++i) {
        int e = e0 + i * 256 + t;
        bb[i] = -1;
        if (e < ETOT) {
            int s, d;
            if (e < N_EDGES) { s = ei[e]; d = ei[N_EDGES + e]; }
            else             { s = d = e - N_EDGES; }
            bb[i] = d >> 8;
            pk[i] = s | ((d & 255) << 16);
            rk[i] = atomicAdd(&hist[bb[i]], 1);
        }
    }
    __syncthreads();
    for (int i = t; i < NBUCK; i += 256)
        lbase[i] = atomicAdd(&tails[i], hist[i]);
    __syncthreads();
#pragma unroll
    for (int i = 0; i < EPT; ++i)
        if (bb[i] >= 0) bdata[bb[i] * BCAP + lbase[bb[i]] + rk[i]] = pk[i];
}

// ---------------- fused: gemm layer-1 blocks + bucketA blocks ----------------
__global__ __launch_bounds__(256) void fusedA(const float* __restrict__ x,
                                              const _Float16* __restrict__ WT1,
                                              const float* __restrict__ att_s,
                                              const float* __restrict__ att_d,
                                              _Float16* __restrict__ H16,
                                              float2* __restrict__ a_src,
                                              float2* __restrict__ a_dst,
                                              const int* __restrict__ ei,
                                              int* __restrict__ tails,
                                              int* __restrict__ bdata) {
    __shared__ _Float16 wt[128][128];   // 32 KB (gemm blocks)
    __shared__ int hist[NBUCK];         // bucketA blocks
    __shared__ int lbase[NBUCK];
    int t = threadIdx.x;
    if (blockIdx.x < GEMMB) {
        gemm_body<true>(blockIdx.x, t, wt, x, WT1, att_s, att_d, H16, a_src, a_dst);
    } else {
        bucketA_body(blockIdx.x - GEMMB, t, hist, lbase, ei, tails, bdata);
    }
}

// ---------------- standalone gemm (layer 2) ----------------
__global__ __launch_bounds__(256) void gemmMFMA(const _Float16* __restrict__ Xin,
                                                const _Float16* __restrict__ WT,
                                                const float* __restrict__ att_s,
                                                const float* __restrict__ att_d,
                                                _Float16* __restrict__ H16,
                                                float2* __restrict__ a_src,
                                                float2* __restrict__ a_dst) {
    __shared__ _Float16 wt[128][128];
    gemm_body<false>(blockIdx.x, threadIdx.x, wt, Xin, WT, att_s, att_d, H16, a_src, a_dst);
}

// ---------------- bucketB: per-bucket CSR fill (self-computed base) ----------------
__global__ __launch_bounds__(256) void bucketB(const int* __restrict__ bdata,
                                               const int* __restrict__ tails,
                                               int* __restrict__ rowptr,
                                               int* __restrict__ csr) {
    __shared__ int hist[256];
    __shared__ int scanws[256];
    int b = blockIdx.x;
    int t = threadIdx.x;

    // scan bucket counts -> this bucket's csr base (replaces scanBuckets kernel)
    int cb = (t < NBUCK) ? tails[t] : 0;
    scanws[t] = cb;
    __syncthreads();
    for (int off = 1; off < 256; off <<= 1) {
        int add = (t >= off) ? scanws[t - off] : 0;
        __syncthreads();
        scanws[t] += add;
        __syncthreads();
    }
    int base = scanws[b] - tails[b];       // exclusive prefix at b (uniform read)
    if (b == NBUCK - 1 && t == 0) rowptr[N_NODES] = scanws[NBUCK - 1];
    int cnt = tails[b];
    int nodes0 = b << 8;
    int nnodes = min(256, N_NODES - nodes0);
    const int* bd = &bdata[b * BCAP];
    __syncthreads();

    hist[t] = 0;
    __syncthreads();
    for (int j = t; j < cnt; j += 256) atomicAdd(&hist[bd[j] >> 16], 1);
    __syncthreads();
    scanws[t] = hist[t];
    __syncthreads();
    for (int off = 1; off < 256; off <<= 1) {
        int add = (t >= off) ? scanws[t - off] : 0;
        __syncthreads();
        scanws[t] += add;
        __syncthreads();
    }
    int excl = scanws[t] - hist[t];
    if (t < nnodes) rowptr[nodes0 + t] = base + excl;
    __syncthreads();
    hist[t] = excl;
    __syncthreads();
    for (int j = t; j < cnt; j += 256) {
        int pkv = bd[j];
        int pos = atomicAdd(&hist[pkv >> 16], 1);
        csr[base + pos] = pkv & 0xFFFF;
    }
}

__device__ __forceinline__ float leaky(float x) { return x > 0.f ? x : NEG * x; }

// ---------------- softmax + aggregation: one wave per dst node ----------------
// R7-verified loop shape: 4 groups of 16 lanes, group g walks every 4th edge,
// lane owns 8 features (one uint4 = 16B load covers the 256B row across the
// group), inline a_src read, unroll 2. Reduce via shfl_xor 16,32.
// POOL=false: write fp16 node output. POOL=true: fused global-mean-pool sums.
template<bool POOL>
__global__ __launch_bounds__(256) void aggk(const __half* __restrict__ H16,
                                            const float2* __restrict__ a_src,
                                            const float2* __restrict__ a_dst,
                                            const int* __restrict__ rowptr,
                                            const int* __restrict__ csr,
                                            const float* __restrict__ bias,
                                            _Float16* __restrict__ out16,
                                            const int* __restrict__ batch,
                                            float* __restrict__ sums) {
    __shared__ float pbuf[POOL ? 4 : 1][128];
    __shared__ int pg[4];
    int t = threadIdx.x;
    int wid = (blockIdx.x * 256 + t) >> 6;    // grid covers exactly N_NODES
    int w = t >> 6;
    int lane = t & 63;
    int rbeg = rowptr[wid], rend = rowptr[wid + 1];
    float2 ad = a_dst[wid];

    int grp = lane >> 4;        // 0..3
    int gl  = lane & 15;        // lane within group: features gl*8..+7
    int head = gl >> 3;         // gl<8 -> head0 (f<64), else head1
    float adh = head ? ad.y : ad.x;
    int f = gl * 8;

    float acc[8] = {0.f, 0.f, 0.f, 0.f, 0.f, 0.f, 0.f, 0.f};
    float denom = 0.f;
#pragma unroll 2
    for (int j = rbeg + grp; j < rend; j += 4) {
        int s = csr[j];
        float2 as = a_src[s];
        float wgt = __expf(leaky((head ? as.y : as.x) + adh));
        uint4 raw = *(const uint4*)&H16[(size_t)s * 128 + f];
        float2 p;
        p = __half22float2(*(__half2*)&raw.x); acc[0] += wgt * p.x; acc[1] += wgt * p.y;
        p = __half22float2(*(__half2*)&raw.y); acc[2] += wgt * p.x; acc[3] += wgt * p.y;
        p = __half22float2(*(__half2*)&raw.z); acc[4] += wgt * p.x; acc[5] += wgt * p.y;
        p = __half22float2(*(__half2*)&raw.w); acc[6] += wgt * p.x; acc[7] += wgt * p.y;
        denom += wgt;
    }
    // reduce across the 4 groups (lane bits 4,5)
#pragma unroll
    for (int off = 16; off <= 32; off <<= 1) {
#pragma unroll
        for (int i = 0; i < 8; ++i) acc[i] += __shfl_xor(acc[i], off);
        denom += __shfl_xor(denom, off);
    }

    float inv = 1.f / (denom + 1e-16f);
    if (POOL) {
        if (grp == 0) {
            if (gl == 0) pg[w] = batch[wid];
#pragma unroll
            for (int i = 0; i < 8; ++i)
                pbuf[w][f + i] = fmaxf(acc[i] * inv + bias[f + i], 0.f);
        }
        __syncthreads();
        // flush: dedupe the 4 wave-slots by graph id, 1 atomic per feat per graph
        if (t < 128) {
#pragma unroll
            for (int ws = 0; ws < 4; ++ws) {
                bool leader = true;
#pragma unroll
                for (int v = 0; v < ws; ++v) leader = leader && (pg[ws] != pg[v]);
                if (leader) {
                    float s = pbuf[ws][t];
#pragma unroll
                    for (int u = ws + 1; u < 4; ++u)
                        if (pg[u] == pg[ws]) s += pbuf[u][t];
                    atomicAdd(&sums[pg[ws] * 128 + t], s);
                }
            }
        }
    } else {
        if (grp == 0) {
            half8 h;
#pragma unroll
            for (int i = 0; i < 8; ++i)
                h[i] = (_Float16)fmaxf(acc[i] * inv + bias[f + i], 0.f);
            *(half8*)&out16[(size_t)wid * 128 + f] = h;
        }
    }
}

// ---------------- final linear (counts via binary search, sorted batch) ----------------
__global__ void finalk(const float* __restrict__ sums, const int* __restrict__ batch,
                       const float* __restrict__ Wl, const float* __restrict__ bl,
                       float* __restrict__ out) {
    int t = threadIdx.x;
    if (t >= GRAPHS * OUTF) return;
    int g = t / OUTF, o = t % OUTF;
    int lo = 0, hi = N_NODES;
    while (lo < hi) { int m = (lo + hi) >> 1; if (batch[m] < g) lo = m + 1; else hi = m; }
    int lb = lo;
    lo = 0; hi = N_NODES;
    while (lo < hi) { int m = (lo + hi) >> 1; if (batch[m] < g + 1) lo = m + 1; else hi = m; }
    float inv = 1.f / fmaxf((float)(lo - lb), 1.f);
    float acc = 0.f;
#pragma unroll 8
    for (int k = 0; k < 128; ++k) acc += sums[g * 128 + k] * Wl[k * OUTF + o];
    out[t] = acc * inv + bl[o];
}

extern "C" void kernel_launch(void* const* d_in, const int* in_sizes, int n_in,
                              void* d_out, int out_size, void* d_ws, size_t ws_size,
                              hipStream_t stream) {
    const float* x        = (const float*)d_in[0];
    const int*   ei       = (const int*)d_in[1];
    const int*   batch    = (const int*)d_in[2];
    const float* W1       = (const float*)d_in[3];
    const float* att_src1 = (const float*)d_in[4];
    const float* att_dst1 = (const float*)d_in[5];
    const float* b1       = (const float*)d_in[6];
    const float* W2       = (const float*)d_in[7];
    const float* att_src2 = (const float*)d_in[8];
    const float* att_dst2 = (const float*)d_in[9];
    const float* b2       = (const float*)d_in[10];
    const float* Wl       = (const float*)d_in[11];
    const float* bl       = (const float*)d_in[12];
    float* out = (float*)d_out;

    size_t off = 0;
    auto alloc = [&](size_t bytes) -> void* {
        void* p = (char*)d_ws + off;
        off = (off + bytes + 255) & ~(size_t)255;
        return p;
    };
    _Float16* H16     = (_Float16*)alloc((size_t)N_NODES * 128 * 2);
    _Float16* B16     = (_Float16*)alloc((size_t)N_NODES * 128 * 2);
    _Float16* WT1     = (_Float16*)alloc(16384 * 2);
    _Float16* WT2     = (_Float16*)alloc(16384 * 2);
    float2*   a_src   = (float2*)alloc((size_t)N_NODES * 8);
    float2*   a_dst   = (float2*)alloc((size_t)N_NODES * 8);
    int*      bdata   = (int*)alloc((size_t)NBUCK * BCAP * 4);
    int*      tails   = (int*)alloc(NBUCK * 4);
    int*      rowptr  = (int*)alloc((size_t)(N_NODES + 1) * 4);
    int*      csr     = (int*)alloc((size_t)ETOT * 4);
    float*    sums    = (float*)alloc((size_t)GRAPHS * HC * 4);

    const int waveBlocks = (N_NODES * 64 + 255) / 256;      // 12500 (exact)

    // 1. setup (weights fp16-transpose, zero tails/sums)
    setupk<<<64, 256, 0, stream>>>(W1, W2, WT1, WT2, tails, sums);
    // 2. layer-1 GEMM + bucketA in one dispatch (independent work)
    fusedA<<<GEMMB + ABLK, 256, 0, stream>>>(x, WT1, att_src1, att_dst1,
                                             H16, a_src, a_dst, ei, tails, bdata);
    // 3. per-bucket CSR fill (self-computes base from tails)
    bucketB<<<NBUCK, 256, 0, stream>>>(bdata, tails, rowptr, csr);
    // 4. layer-1 aggregation (writes fp16 node features)
    aggk<false><<<waveBlocks, 256, 0, stream>>>((const __half*)H16, a_src, a_dst,
                                                rowptr, csr, b1, B16, batch, sums);
    // 5. layer-2 GEMM
    gemmMFMA<<<GEMMB, 256, 0, stream>>>(B16, WT2, att_src2, att_dst2,
                                        H16, a_src, a_dst);
    // 6. layer-2 aggregation + fused global-mean-pool sums
    aggk<true><<<waveBlocks, 256, 0, stream>>>((const __half*)H16, a_src, a_dst,
                                               rowptr, csr, b2, nullptr, batch, sums);
    // 7. final linear (+ per-graph counts via binary search)
    finalk<<<1, 640, 0, stream>>>(sums, batch, Wl, bl, out);
}